// Round 7
// baseline (2105.541 us; speedup 1.0000x reference)
//
#include <hip/hip_runtime.h>

#define Gn 4
#define Nn 50000
#define En 800000
#define Bq 32
#define F_IN 64
#define Hn 128
#define HEADS 8
#define HD 16
#define NNODES 50000
#define NB 196     // (Nn+255)/256
#define RANGE 3125 // Nn / 16
#define RPG 16     // ranges per graph

using v8s = __attribute__((ext_vector_type(8))) short;
using v4f = __attribute__((ext_vector_type(4))) float;

// ---- bf16 helpers (RNE) ----
__device__ __forceinline__ float bf2f(unsigned short u) {
    unsigned int x = ((unsigned int)u) << 16;
    float f; __builtin_memcpy(&f, &x, 4); return f;
}
__device__ __forceinline__ unsigned short f2bf(float f) {
    unsigned int x; __builtin_memcpy(&x, &f, 4);
    x = (x + 0x7fffu + ((x >> 16) & 1u)) >> 16;
    return (unsigned short)x;
}

// ---------------- degree histogram, node-range partitioned, LDS-only atomics ----------------
// block = (range r, graph g); streams col, counts dests in [r*RANGE, (r+1)*RANGE).
__global__ __launch_bounds__(256) void k_hist(const int* __restrict__ ei, int* __restrict__ degi) {
    __shared__ int h[RANGE];
    int g = blockIdx.y;
    int lo = blockIdx.x * RANGE;
    const int4* col4 = (const int4*)(ei + (size_t)g * 2 * En + En);
    for (int i = threadIdx.x; i < RANGE; i += 256) h[i] = 0;
    __syncthreads();
    for (int i = threadIdx.x; i < En / 4; i += 256) {
        int4 c = col4[i];
        unsigned int d;
        d = (unsigned int)(c.x - lo); if (d < RANGE) atomicAdd(&h[d], 1);
        d = (unsigned int)(c.y - lo); if (d < RANGE) atomicAdd(&h[d], 1);
        d = (unsigned int)(c.z - lo); if (d < RANGE) atomicAdd(&h[d], 1);
        d = (unsigned int)(c.w - lo); if (d < RANGE) atomicAdd(&h[d], 1);
    }
    __syncthreads();
    int* dg = degi + g * Nn + lo;
    for (int i = threadIdx.x; i < RANGE; i += 256) dg[i] = h[i];
}

// ---------------- scan stage 1: per-block sums ----------------
__global__ __launch_bounds__(256) void k_bsum4(const int* __restrict__ degi, int* __restrict__ bsum) {
    __shared__ int red[4];
    int g = blockIdx.y;
    int i = blockIdx.x * 256 + threadIdx.x;
    int v = (i < Nn) ? degi[g * Nn + i] : 0;
#pragma unroll
    for (int off = 32; off > 0; off >>= 1) v += __shfl_down(v, off, 64);
    if ((threadIdx.x & 63) == 0) red[threadIdx.x >> 6] = v;
    __syncthreads();
    if (threadIdx.x == 0) bsum[g * 256 + blockIdx.x] = red[0] + red[1] + red[2] + red[3];
}

// ---------------- scan stage 2: exclusive scan of NB block sums per graph ----------------
__global__ __launch_bounds__(256) void k_bscan4(int* __restrict__ bsum) {
    __shared__ int s[256];
    int g = blockIdx.x, t = threadIdx.x;
    int v = (t < NB) ? bsum[g * 256 + t] : 0;
    s[t] = v;
    __syncthreads();
    for (int d = 1; d < 256; d <<= 1) {
        int u = (t >= d) ? s[t - d] : 0;
        __syncthreads();
        s[t] += u;
        __syncthreads();
    }
    if (t < NB) bsum[g * 256 + t] = (t > 0) ? s[t - 1] : 0;
}

// ---------------- scan stage 3: offsets + dinv ----------------
__global__ __launch_bounds__(256) void k_off4(const int* __restrict__ degi, const int* __restrict__ bbase,
                                              int* __restrict__ off, float* __restrict__ dinv) {
    __shared__ int s[256];
    int g = blockIdx.y, b = blockIdx.x, t = threadIdx.x;
    int i = b * 256 + t;
    int d = (i < Nn) ? degi[g * Nn + i] : 0;
    s[t] = d;
    __syncthreads();
    for (int dd = 1; dd < 256; dd <<= 1) {
        int u = (t >= dd) ? s[t - dd] : 0;
        __syncthreads();
        s[t] += u;
        __syncthreads();
    }
    if (i < Nn) {
        int base = bbase[g * 256 + b];
        off[g * (Nn + 1) + i] = base + s[t] - d;
        dinv[g * Nn + i] = rsqrtf((float)d + 1.0f);
        if (i == Nn - 1) off[g * (Nn + 1) + Nn] = base + s[t];
    }
}

// ---------------- CSR fill, node-range partitioned, LDS cursors (no global atomics) ----------------
// Scattered srcs writes stay inside this block's private contiguous region (~100 KB) -> L2-local.
__global__ __launch_bounds__(256) void k_fillr(const int* __restrict__ ei, const int* __restrict__ off,
                                               unsigned short* __restrict__ srcs) {
    __shared__ int curL[RANGE];
    int g = blockIdx.y;
    int lo = blockIdx.x * RANGE;
    const int* row = ei + (size_t)g * 2 * En;
    const int4* col4 = (const int4*)(row + En);
    const int* offg = off + g * (Nn + 1) + lo;
    unsigned short* sg = srcs + (size_t)g * En;
    for (int i = threadIdx.x; i < RANGE; i += 256) curL[i] = offg[i];
    __syncthreads();
    for (int i = threadIdx.x; i < En / 4; i += 256) {
        int4 c = col4[i];
        int e = i * 4;
        unsigned int d;
        d = (unsigned int)(c.x - lo);
        if (d < RANGE) { int pos = atomicAdd(&curL[d], 1); sg[pos] = (unsigned short)row[e + 0]; }
        d = (unsigned int)(c.y - lo);
        if (d < RANGE) { int pos = atomicAdd(&curL[d], 1); sg[pos] = (unsigned short)row[e + 1]; }
        d = (unsigned int)(c.z - lo);
        if (d < RANGE) { int pos = atomicAdd(&curL[d], 1); sg[pos] = (unsigned short)row[e + 2]; }
        d = (unsigned int)(c.w - lo);
        if (d < RANGE) { int pos = atomicAdd(&curL[d], 1); sg[pos] = (unsigned short)row[e + 3]; }
    }
}

// ---------------- cast + pre-scale: xbs = bf16(x * dinv) ----------------
__global__ __launch_bounds__(256) void k_cast(const float* __restrict__ x, const float* __restrict__ dinv,
                                              unsigned short* __restrict__ xbs) {
    int i = blockIdx.x * 256 + threadIdx.x;  // one float4 per thread, N*16 total
    if (i >= Nn * 16) return;
    float dc = dinv[i >> 4];
    float4 v = *(const float4*)&x[i * 4];
    ushort4 u = make_ushort4(f2bf(v.x * dc), f2bf(v.y * dc), f2bf(v.z * dc), f2bf(v.w * dc));
    *(ushort4*)&xbs[i * 4] = u;
}

// ---------------- agg 64-feat: z1 = dinv_c * (sum_e xs_r + xs_c) ----------------
__global__ __launch_bounds__(256) void k_agg1(const unsigned short* __restrict__ xs, const int* __restrict__ off,
                                              const unsigned short* __restrict__ srcs,
                                              const float* __restrict__ dinv, unsigned short* __restrict__ z1) {
    int node = blockIdx.x * 8 + (threadIdx.x >> 5);
    int lane = threadIdx.x & 31;
    int f2 = lane << 1;
    int beg = off[node], end = off[node + 1];
    ushort2 own = *(const ushort2*)&xs[(long)node * 64 + f2];
    float ax = bf2f(own.x), ay = bf2f(own.y);
    for (int e = beg; e < end; e += 32) {
        int k = min(32, end - e);
        int sid = 0;
        if (lane < k) sid = srcs[e + lane];
        for (int j = 0; j < k; ++j) {
            int s = __shfl(sid, j, 32);
            ushort2 u = *(const ushort2*)&xs[(long)s * 64 + f2];
            ax += bf2f(u.x);
            ay += bf2f(u.y);
        }
    }
    float dc = dinv[node];
    *(ushort2*)&z1[(long)node * 64 + f2] = make_ushort2(f2bf(ax * dc), f2bf(ay * dc));
}

// ---------------- agg 128-feat: z2 = dinv_c * (sum_e y1s_r + y1s_c) ----------------
__global__ __launch_bounds__(256) void k_agg2(const unsigned short* __restrict__ h, const int* __restrict__ off,
                                              const unsigned short* __restrict__ srcs,
                                              const float* __restrict__ dinv, unsigned short* __restrict__ z2) {
    int node = blockIdx.x * 8 + (threadIdx.x >> 5);
    int lane = threadIdx.x & 31;
    int f4 = lane << 2;
    int beg = off[node], end = off[node + 1];
    ushort4 own = *(const ushort4*)&h[(long)node * 128 + f4];
    float a0 = bf2f(own.x), a1 = bf2f(own.y), a2 = bf2f(own.z), a3 = bf2f(own.w);
    for (int e = beg; e < end; e += 32) {
        int k = min(32, end - e);
        int sid = 0;
        if (lane < k) sid = srcs[e + lane];
        for (int j = 0; j < k; ++j) {
            int s = __shfl(sid, j, 32);
            ushort4 u = *(const ushort4*)&h[(long)s * 128 + f4];
            a0 += bf2f(u.x);
            a1 += bf2f(u.y);
            a2 += bf2f(u.z);
            a3 += bf2f(u.w);
        }
    }
    float dc = dinv[node];
    *(ushort4*)&z2[(long)node * 128 + f4] =
        make_ushort4(f2bf(a0 * dc), f2bf(a1 * dc), f2bf(a2 * dc), f2bf(a3 * dc));
}

// ---------------- MFMA mm: out_bf16 = relu(zin[N,K]bf16 @ W[K,128]f32 + b) [* dinv if SCALE] ----------------
template <int K, bool SCALE>
__global__ __launch_bounds__(256) void k_mmfma(const unsigned short* __restrict__ zin,
                                               const float* __restrict__ W, const float* __restrict__ bias,
                                               const float* __restrict__ dinv,
                                               unsigned short* __restrict__ outp, int nrows) {
    __shared__ __align__(16) unsigned short Wt[128 * (K + 8)];  // W transposed [n][k], bf16, +8 pad
    __shared__ __align__(16) unsigned short At[32 * (K + 8)];   // A rows [r][k], bf16
    int t = threadIdx.x;
    int base = blockIdx.x * 32;

#pragma unroll
    for (int i = 0; i < K * 128 / 256; ++i) {
        int idx = i * 256 + t;
        int k = idx >> 7, n = idx & 127;
        Wt[n * (K + 8) + k] = f2bf(W[idx]);
    }
    {
        int r = t >> 3, cb = (t & 7) * (K / 8);
        long grow = base + r;
#pragma unroll
        for (int j = 0; j < K / 32; ++j) {
            ushort4 u = make_ushort4(0, 0, 0, 0);
            if (grow < nrows) u = *(const ushort4*)&zin[grow * K + cb + j * 4];
            *(ushort4*)&At[r * (K + 8) + cb + j * 4] = u;
        }
    }
    __syncthreads();

    int w = t >> 6, lane = t & 63;
    int wm = w & 1, wn = w >> 1;
    int m = lane & 15, q = lane >> 4;
    v4f acc[4] = {};
    const unsigned short* Ap = &At[(wm * 16 + m) * (K + 8) + q * 8];
    const unsigned short* Bp = &Wt[(wn * 64 + m) * (K + 8) + q * 8];
    const int rstep = 16 * (K + 8);
#pragma unroll
    for (int ks = 0; ks < K / 32; ++ks) {
        v8s a = *(const v8s*)(Ap + ks * 32);
        v8s b0 = *(const v8s*)(Bp + 0 * rstep + ks * 32);
        v8s b1 = *(const v8s*)(Bp + 1 * rstep + ks * 32);
        v8s b2 = *(const v8s*)(Bp + 2 * rstep + ks * 32);
        v8s b3 = *(const v8s*)(Bp + 3 * rstep + ks * 32);
        acc[0] = __builtin_amdgcn_mfma_f32_16x16x32_bf16(a, b0, acc[0], 0, 0, 0);
        acc[1] = __builtin_amdgcn_mfma_f32_16x16x32_bf16(a, b1, acc[1], 0, 0, 0);
        acc[2] = __builtin_amdgcn_mfma_f32_16x16x32_bf16(a, b2, acc[2], 0, 0, 0);
        acc[3] = __builtin_amdgcn_mfma_f32_16x16x32_bf16(a, b3, acc[3], 0, 0, 0);
    }

    int col0 = wn * 64 + m;
    int rbase = base + wm * 16 + q * 4;
    float dv[4];
#pragma unroll
    for (int rg = 0; rg < 4; ++rg)
        dv[rg] = SCALE ? ((rbase + rg < nrows) ? dinv[rbase + rg] : 1.f) : 1.f;
#pragma unroll
    for (int nt = 0; nt < 4; ++nt) {
        float bc = bias[col0 + nt * 16];
#pragma unroll
        for (int rg = 0; rg < 4; ++rg) {
            int row = rbase + rg;
            if (row < nrows) {
                float o = fmaxf(acc[nt][rg] + bc, 0.f);
                outp[(long)row * 128 + col0 + nt * 16] = f2bf(o * dv[rg]);
            }
        }
    }
}

// ---------------- segment mean pool (batch sorted), bf16 input ----------------
__global__ __launch_bounds__(128) void k_pool(const unsigned short* __restrict__ y, const int* __restrict__ batch,
                                              float* __restrict__ emb_sum, float* __restrict__ cnt, int g) {
    int f = threadIdx.x;  // 128
    int start = blockIdx.x * 64;
    int end = min(start + 64, Nn);
    if (start >= Nn) return;
    float acc = 0.f;
    int cacc = 0;
    int cur = batch[start];
    for (int i = start; i < end; ++i) {
        int b = batch[i];
        if (b != cur) {
            atomicAdd(&emb_sum[(g * Bq + cur) * Hn + f], acc);
            if (f == 0) atomicAdd(&cnt[g * Bq + cur], (float)cacc);
            acc = 0.f; cacc = 0; cur = b;
        }
        acc += bf2f(y[(long)i * Hn + f]);
        cacc++;
    }
    atomicAdd(&emb_sum[(g * Bq + cur) * Hn + f], acc);
    if (f == 0) atomicAdd(&cnt[g * Bq + cur], (float)cacc);
}

// ---------------- whole MHA: one block per batch element b ----------------
__global__ __launch_bounds__(128) void k_attn(const float* __restrict__ emb_sum, const float* __restrict__ cnt,
                                              const float* __restrict__ ipw, const float* __restrict__ ipb,
                                              const float* __restrict__ opw, const float* __restrict__ opb,
                                              float* __restrict__ pooled) {
    int b = blockIdx.x;
    int f = threadIdx.x;  // 128
    __shared__ float es[4][128], qs[4][128], ks[4][128], vs[4][128], sc[128], cx[4][128];
#pragma unroll
    for (int g = 0; g < 4; ++g) {
        float c = cnt[g * Bq + b];
        es[g][f] = (c > 0.f) ? emb_sum[(g * Bq + b) * Hn + f] / c : 0.f;
    }
    __syncthreads();
#pragma unroll
    for (int g = 0; g < 4; ++g) {
        float q = ipb[f], k = ipb[Hn + f], v = ipb[2 * Hn + f];
        for (int j = 0; j < Hn; ++j) {
            float e = es[g][j];
            q += e * ipw[f * Hn + j];
            k += e * ipw[(Hn + f) * Hn + j];
            v += e * ipw[(2 * Hn + f) * Hn + j];
        }
        qs[g][f] = q; ks[g][f] = k; vs[g][f] = v;
    }
    __syncthreads();
    {
        int h = f >> 4, g = (f >> 2) & 3, kk = f & 3;
        float s = 0.f;
        for (int d = 0; d < 16; ++d) s += qs[g][h * 16 + d] * ks[kk][h * 16 + d];
        sc[f] = s * 0.25f;
    }
    __syncthreads();
    {
        int h = f >> 4;
#pragma unroll
        for (int g = 0; g < 4; ++g) {
            int bi = h * 16 + g * 4;
            float s0 = sc[bi], s1 = sc[bi + 1], s2 = sc[bi + 2], s3 = sc[bi + 3];
            float m = fmaxf(fmaxf(s0, s1), fmaxf(s2, s3));
            float e0 = __expf(s0 - m), e1 = __expf(s1 - m), e2 = __expf(s2 - m), e3 = __expf(s3 - m);
            float rinv = 1.f / (e0 + e1 + e2 + e3);
            cx[g][f] = (e0 * vs[0][f] + e1 * vs[1][f] + e2 * vs[2][f] + e3 * vs[3][f]) * rinv;
        }
    }
    __syncthreads();
#pragma unroll
    for (int g = 0; g < 4; ++g) {
        float a = opb[f];
        for (int j = 0; j < Hn; ++j) a += cx[g][j] * opw[f * Hn + j];
        atomicAdd(&pooled[g * Hn + f], a * (1.0f / Bq));
    }
}

// ---------------- final: out[g,n] = (pooled[g] . lin_w[n] + lin_b[n]) * 60 + 50 ----------------
__global__ __launch_bounds__(256) void k_final(const float* __restrict__ pooled, const float* __restrict__ lw,
                                               const float* __restrict__ lb, float* __restrict__ out) {
    __shared__ float ps[512];
    int t = threadIdx.x;
    ps[t] = pooled[t];
    ps[t + 256] = pooled[t + 256];
    __syncthreads();
    int wave = t >> 6, lane = t & 63;
    int n = blockIdx.x * 4 + wave;
    if (n >= NNODES) return;
    float2 w = *(const float2*)&lw[(long)n * 128 + lane * 2];
    float a0 = w.x * ps[0 * 128 + lane * 2] + w.y * ps[0 * 128 + lane * 2 + 1];
    float a1 = w.x * ps[1 * 128 + lane * 2] + w.y * ps[1 * 128 + lane * 2 + 1];
    float a2 = w.x * ps[2 * 128 + lane * 2] + w.y * ps[2 * 128 + lane * 2 + 1];
    float a3 = w.x * ps[3 * 128 + lane * 2] + w.y * ps[3 * 128 + lane * 2 + 1];
#pragma unroll
    for (int off = 32; off > 0; off >>= 1) {
        a0 += __shfl_down(a0, off);
        a1 += __shfl_down(a1, off);
        a2 += __shfl_down(a2, off);
        a3 += __shfl_down(a3, off);
    }
    if (lane == 0) {
        float bn = lb[n];
        out[0 * NNODES + n] = (a0 + bn) * 60.f + 50.f;
        out[1 * NNODES + n] = (a1 + bn) * 60.f + 50.f;
        out[2 * NNODES + n] = (a2 + bn) * 60.f + 50.f;
        out[3 * NNODES + n] = (a3 + bn) * 60.f + 50.f;
    }
}

extern "C" void kernel_launch(void* const* d_in, const int* in_sizes, int n_in,
                              void* d_out, int out_size, void* d_ws, size_t ws_size,
                              hipStream_t stream) {
    const float* x   = (const float*)d_in[0];
    const int*   ei  = (const int*)d_in[1];
    const int*   bat = (const int*)d_in[2];
    const float* W1  = (const float*)d_in[3];
    const float* b1  = (const float*)d_in[4];
    const float* W2  = (const float*)d_in[5];
    const float* b2  = (const float*)d_in[6];
    const float* ipw = (const float*)d_in[7];
    const float* ipb = (const float*)d_in[8];
    const float* opw = (const float*)d_in[9];
    const float* opb = (const float*)d_in[10];
    const float* lw  = (const float*)d_in[11];
    const float* lb  = (const float*)d_in[12];
    float* out = (float*)d_out;

    // workspace carve-up (~60 MB)
    char* p = (char*)d_ws;
    unsigned short* xbs = (unsigned short*)p;                // [N,64]  bf16    6.4 MB
    unsigned short* z1  = xbs + (size_t)Nn * 64;             // [N,64]  bf16    6.4 MB
    unsigned short* y1b = (unsigned short*)(p + 12800000);   // [N,128] bf16   12.8 MB
    unsigned short* z2  = (unsigned short*)(p + 25600000);   // [N,128] bf16   12.8 MB
    unsigned short* y2b = (unsigned short*)(p + 38400000);   // [N,128] bf16   12.8 MB
    int*   degi = (int*)(p + 51200000);                      // [4][N]
    int*   off  = degi + 4 * Nn;                             // [4][N+1]
    float* dinv = (float*)(off + 4 * (Nn + 1));              // [4][N]
    int*   bsum = (int*)(dinv + 4 * Nn);                     // [4][256]
    unsigned short* srcs = (unsigned short*)(bsum + 4 * 256);// [4][E] ushort
    float* emb    = (float*)(srcs + (size_t)4 * En);         // [G,B,H]
    float* cnt    = emb + Gn * Bq * Hn;                      // [G,B]
    float* pooled = cnt + Gn * Bq;                           // [G,H]

    hipMemsetAsync(emb, 0, Gn * Bq * Hn * sizeof(float), stream);
    hipMemsetAsync(cnt, 0, Gn * Bq * sizeof(float), stream);
    hipMemsetAsync(pooled, 0, Gn * Hn * sizeof(float), stream);

    const int agGrid = (Nn + 7) / 8;                 // 6250
    const int mmGrid = (Nn + 31) / 32;               // 1563
    const int plGrid = (Nn + 63) / 64;               // 782
    const int ctGrid = (Nn * 16 + 255) / 256;        // 3125

    // CSR build: LDS histogram -> scan -> LDS-cursor fill (no global atomics anywhere)
    k_hist<<<dim3(RPG, 4), 256, 0, stream>>>(ei, degi);
    k_bsum4<<<dim3(NB, 4), 256, 0, stream>>>(degi, bsum);
    k_bscan4<<<4, 256, 0, stream>>>(bsum);
    k_off4<<<dim3(NB, 4), 256, 0, stream>>>(degi, bsum, off, dinv);
    k_fillr<<<dim3(RPG, 4), 256, 0, stream>>>(ei, off, srcs);

    for (int g = 0; g < Gn; ++g) {
        const float* xg = x + (size_t)g * Nn * F_IN;
        const int* bg = bat + (size_t)g * Nn;
        const int* offg = off + g * (Nn + 1);
        const float* dinvg = dinv + g * Nn;
        const unsigned short* srcg = srcs + (size_t)g * En;

        k_cast<<<ctGrid, 256, 0, stream>>>(xg, dinvg, xbs);

        // layer 1: z1 = dinv*(sum xs + xs_self); y1s = relu(z1@W1+b1)*dinv
        k_agg1<<<agGrid, 256, 0, stream>>>(xbs, offg, srcg, dinvg, z1);
        k_mmfma<64, true><<<mmGrid, 256, 0, stream>>>(z1, W1, b1, dinvg, y1b, Nn);

        // layer 2: z2 = dinv*(sum y1s + y1s_self); y2 = relu(z2@W2+b2)
        k_agg2<<<agGrid, 256, 0, stream>>>(y1b, offg, srcg, dinvg, z2);
        k_mmfma<128, false><<<mmGrid, 256, 0, stream>>>(z2, W2, b2, dinvg, y2b, Nn);

        // pool
        k_pool<<<plGrid, 128, 0, stream>>>(y2b, bg, emb, cnt, g);
    }

    k_attn<<<Bq, 128, 0, stream>>>(emb, cnt, ipw, ipb, opw, opb, pooled);
    k_final<<<(NNODES + 3) / 4, 256, 0, stream>>>(pooled, lw, lb, out);
}

// Round 8
// 766.703 us; speedup vs baseline: 2.7462x; 2.7462x over previous
//
#include <hip/hip_runtime.h>

#define Gn 4
#define Nn 50000
#define En 800000
#define Bq 32
#define F_IN 64
#define Hn 128
#define HEADS 8
#define HD 16
#define NNODES 50000
#define NB 196      // (Nn+255)/256 scan blocks
#define NBK 196     // dest buckets per graph (dest >> 8)
#define EB 98       // edge chunks per graph (8192 edges each)

using v8s = __attribute__((ext_vector_type(8))) short;
using v4f = __attribute__((ext_vector_type(4))) float;

// ---- bf16 helpers (RNE) ----
__device__ __forceinline__ float bf2f(unsigned short u) {
    unsigned int x = ((unsigned int)u) << 16;
    float f; __builtin_memcpy(&f, &x, 4); return f;
}
__device__ __forceinline__ unsigned short f2bf(float f) {
    unsigned int x; __builtin_memcpy(&x, &f, 4);
    x = (x + 0x7fffu + ((x >> 16) & 1u)) >> 16;
    return (unsigned short)x;
}

// ---------------- phase 1: coarse bucket totals (bucket = dest>>8) ----------------
__global__ __launch_bounds__(256) void k_btot(const int* __restrict__ ei, int* __restrict__ btot) {
    __shared__ int h[NBK];
    int g = blockIdx.y;
    const int* col = ei + (size_t)g * 2 * En + En;
    for (int i = threadIdx.x; i < NBK; i += 256) h[i] = 0;
    __syncthreads();
    int e0 = blockIdx.x * 8192, e1 = min(e0 + 8192, En);
    for (int i = e0 / 4 + threadIdx.x; i < e1 / 4; i += 256) {
        int4 c = ((const int4*)col)[i];
        atomicAdd(&h[c.x >> 8], 1);
        atomicAdd(&h[c.y >> 8], 1);
        atomicAdd(&h[c.z >> 8], 1);
        atomicAdd(&h[c.w >> 8], 1);
    }
    __syncthreads();
    for (int i = threadIdx.x; i < NBK; i += 256)
        if (h[i]) atomicAdd(&btot[g * NBK + i], h[i]);
}

// ---------------- phase 2: scan bucket totals -> bases + global cursors ----------------
__global__ __launch_bounds__(256) void k_bbase(const int* __restrict__ btot, int* __restrict__ bbase,
                                               int* __restrict__ bcur) {
    __shared__ int s[256];
    int g = blockIdx.x, t = threadIdx.x;
    int v = (t < NBK) ? btot[g * NBK + t] : 0;
    s[t] = v;
    __syncthreads();
    for (int d = 1; d < 256; d <<= 1) {
        int u = (t >= d) ? s[t - d] : 0;
        __syncthreads();
        s[t] += u;
        __syncthreads();
    }
    if (t < NBK) { int b = s[t] - v; bbase[g * NBK + t] = b; bcur[g * NBK + t] = b; }
}

// ---------------- phase 3: bucketize edges into packed pairs (r<<16|c) ----------------
// One coarse atomicAdd per (block,bucket); pair writes are short contiguous runs.
__global__ __launch_bounds__(256) void k_bucket(const int* __restrict__ ei, int* __restrict__ bcur,
                                                unsigned int* __restrict__ pairs) {
    __shared__ int h[NBK];
    __shared__ int gbase[NBK];
    int g = blockIdx.y;
    const int* row = ei + (size_t)g * 2 * En;
    const int* col = row + En;
    unsigned int* pg = pairs + (size_t)g * En;
    for (int i = threadIdx.x; i < NBK; i += 256) h[i] = 0;
    __syncthreads();
    int e0 = blockIdx.x * 8192, e1 = min(e0 + 8192, En);
    for (int i = e0 / 4 + threadIdx.x; i < e1 / 4; i += 256) {
        int4 c = ((const int4*)col)[i];
        atomicAdd(&h[c.x >> 8], 1);
        atomicAdd(&h[c.y >> 8], 1);
        atomicAdd(&h[c.z >> 8], 1);
        atomicAdd(&h[c.w >> 8], 1);
    }
    __syncthreads();
    for (int i = threadIdx.x; i < NBK; i += 256) {
        int cnt = h[i];
        gbase[i] = cnt ? atomicAdd(&bcur[g * NBK + i], cnt) : 0;
        h[i] = 0;  // becomes local cursor
    }
    __syncthreads();
    for (int i = e0 / 4 + threadIdx.x; i < e1 / 4; i += 256) {
        int4 c = ((const int4*)col)[i];
        int4 r = ((const int4*)row)[i];
        int p;
        p = gbase[c.x >> 8] + atomicAdd(&h[c.x >> 8], 1); pg[p] = ((unsigned)r.x << 16) | (unsigned)c.x;
        p = gbase[c.y >> 8] + atomicAdd(&h[c.y >> 8], 1); pg[p] = ((unsigned)r.y << 16) | (unsigned)c.y;
        p = gbase[c.z >> 8] + atomicAdd(&h[c.z >> 8], 1); pg[p] = ((unsigned)r.z << 16) | (unsigned)c.z;
        p = gbase[c.w >> 8] + atomicAdd(&h[c.w >> 8], 1); pg[p] = ((unsigned)r.w << 16) | (unsigned)c.w;
    }
}

// ---------------- phase 4: per-bucket degree (256 nodes/bucket, LDS count) ----------------
__global__ __launch_bounds__(256) void k_degb(const unsigned int* __restrict__ pairs,
                                              const int* __restrict__ bbase, const int* __restrict__ btot,
                                              int* __restrict__ degi) {
    __shared__ int h[256];
    int g = blockIdx.y, b = blockIdx.x, t = threadIdx.x;
    int beg = bbase[g * NBK + b], cnt = btot[g * NBK + b];
    const unsigned int* pg = pairs + (size_t)g * En + beg;
    h[t] = 0;
    __syncthreads();
    for (int i = t; i < cnt; i += 256) atomicAdd(&h[pg[i] & 255], 1);
    __syncthreads();
    int node = b * 256 + t;
    if (node < Nn) degi[g * Nn + node] = h[t];
}

// ---------------- scan stage 1: per-block sums ----------------
__global__ __launch_bounds__(256) void k_bsum4(const int* __restrict__ degi, int* __restrict__ bsum) {
    __shared__ int red[4];
    int g = blockIdx.y;
    int i = blockIdx.x * 256 + threadIdx.x;
    int v = (i < Nn) ? degi[g * Nn + i] : 0;
#pragma unroll
    for (int off = 32; off > 0; off >>= 1) v += __shfl_down(v, off, 64);
    if ((threadIdx.x & 63) == 0) red[threadIdx.x >> 6] = v;
    __syncthreads();
    if (threadIdx.x == 0) bsum[g * 256 + blockIdx.x] = red[0] + red[1] + red[2] + red[3];
}

// ---------------- scan stage 2: exclusive scan of NB block sums per graph ----------------
__global__ __launch_bounds__(256) void k_bscan4(int* __restrict__ bsum) {
    __shared__ int s[256];
    int g = blockIdx.x, t = threadIdx.x;
    int v = (t < NB) ? bsum[g * 256 + t] : 0;
    s[t] = v;
    __syncthreads();
    for (int d = 1; d < 256; d <<= 1) {
        int u = (t >= d) ? s[t - d] : 0;
        __syncthreads();
        s[t] += u;
        __syncthreads();
    }
    if (t < NB) bsum[g * 256 + t] = (t > 0) ? s[t - 1] : 0;
}

// ---------------- scan stage 3: offsets + dinv ----------------
__global__ __launch_bounds__(256) void k_off4(const int* __restrict__ degi, const int* __restrict__ bbase,
                                              int* __restrict__ off, float* __restrict__ dinv) {
    __shared__ int s[256];
    int g = blockIdx.y, b = blockIdx.x, t = threadIdx.x;
    int i = b * 256 + t;
    int d = (i < Nn) ? degi[g * Nn + i] : 0;
    s[t] = d;
    __syncthreads();
    for (int dd = 1; dd < 256; dd <<= 1) {
        int u = (t >= dd) ? s[t - dd] : 0;
        __syncthreads();
        s[t] += u;
        __syncthreads();
    }
    if (i < Nn) {
        int base = bbase[g * 256 + b];
        off[g * (Nn + 1) + i] = base + s[t] - d;
        dinv[g * Nn + i] = rsqrtf((float)d + 1.0f);
        if (i == Nn - 1) off[g * (Nn + 1) + Nn] = base + s[t];
    }
}

// ---------------- phase 6: per-bucket CSR fill via LDS cursors ----------------
// srcs writes confined to this bucket's private ~8KB contiguous region.
__global__ __launch_bounds__(256) void k_fillb(const unsigned int* __restrict__ pairs,
                                               const int* __restrict__ bbase, const int* __restrict__ btot,
                                               const int* __restrict__ off, unsigned short* __restrict__ srcs) {
    __shared__ int curL[256];
    int g = blockIdx.y, b = blockIdx.x, t = threadIdx.x;
    int lo = b * 256;
    int beg = bbase[g * NBK + b], cnt = btot[g * NBK + b];
    const unsigned int* pg = pairs + (size_t)g * En + beg;
    const int* offg = off + g * (Nn + 1);
    unsigned short* sg = srcs + (size_t)g * En;
    curL[t] = (lo + t < Nn) ? offg[lo + t] : 0;
    __syncthreads();
    for (int i = t; i < cnt; i += 256) {
        unsigned int pr = pg[i];
        int pos = atomicAdd(&curL[pr & 255], 1);
        sg[pos] = (unsigned short)(pr >> 16);
    }
}

// ---------------- cast + pre-scale: xbs = bf16(x * dinv) ----------------
__global__ __launch_bounds__(256) void k_cast(const float* __restrict__ x, const float* __restrict__ dinv,
                                              unsigned short* __restrict__ xbs) {
    int i = blockIdx.x * 256 + threadIdx.x;
    if (i >= Nn * 16) return;
    float dc = dinv[i >> 4];
    float4 v = *(const float4*)&x[i * 4];
    ushort4 u = make_ushort4(f2bf(v.x * dc), f2bf(v.y * dc), f2bf(v.z * dc), f2bf(v.w * dc));
    *(ushort4*)&xbs[i * 4] = u;
}

// ---------------- agg 64-feat: z1 = dinv_c * (sum_e xs_r + xs_c) ----------------
__global__ __launch_bounds__(256) void k_agg1(const unsigned short* __restrict__ xs, const int* __restrict__ off,
                                              const unsigned short* __restrict__ srcs,
                                              const float* __restrict__ dinv, unsigned short* __restrict__ z1) {
    int node = blockIdx.x * 8 + (threadIdx.x >> 5);
    int lane = threadIdx.x & 31;
    int f2 = lane << 1;
    int beg = off[node], end = off[node + 1];
    ushort2 own = *(const ushort2*)&xs[(long)node * 64 + f2];
    float ax = bf2f(own.x), ay = bf2f(own.y);
    for (int e = beg; e < end; e += 32) {
        int k = min(32, end - e);
        int sid = 0;
        if (lane < k) sid = srcs[e + lane];
        for (int j = 0; j < k; ++j) {
            int s = __shfl(sid, j, 32);
            ushort2 u = *(const ushort2*)&xs[(long)s * 64 + f2];
            ax += bf2f(u.x);
            ay += bf2f(u.y);
        }
    }
    float dc = dinv[node];
    *(ushort2*)&z1[(long)node * 64 + f2] = make_ushort2(f2bf(ax * dc), f2bf(ay * dc));
}

// ---------------- agg 128-feat: z2 = dinv_c * (sum_e y1s_r + y1s_c) ----------------
__global__ __launch_bounds__(256) void k_agg2(const unsigned short* __restrict__ h, const int* __restrict__ off,
                                              const unsigned short* __restrict__ srcs,
                                              const float* __restrict__ dinv, unsigned short* __restrict__ z2) {
    int node = blockIdx.x * 8 + (threadIdx.x >> 5);
    int lane = threadIdx.x & 31;
    int f4 = lane << 2;
    int beg = off[node], end = off[node + 1];
    ushort4 own = *(const ushort4*)&h[(long)node * 128 + f4];
    float a0 = bf2f(own.x), a1 = bf2f(own.y), a2 = bf2f(own.z), a3 = bf2f(own.w);
    for (int e = beg; e < end; e += 32) {
        int k = min(32, end - e);
        int sid = 0;
        if (lane < k) sid = srcs[e + lane];
        for (int j = 0; j < k; ++j) {
            int s = __shfl(sid, j, 32);
            ushort4 u = *(const ushort4*)&h[(long)s * 128 + f4];
            a0 += bf2f(u.x);
            a1 += bf2f(u.y);
            a2 += bf2f(u.z);
            a3 += bf2f(u.w);
        }
    }
    float dc = dinv[node];
    *(ushort4*)&z2[(long)node * 128 + f4] =
        make_ushort4(f2bf(a0 * dc), f2bf(a1 * dc), f2bf(a2 * dc), f2bf(a3 * dc));
}

// ---------------- MFMA mm: out_bf16 = relu(zin[N,K]bf16 @ W[K,128]f32 + b) [* dinv if SCALE] ----------------
template <int K, bool SCALE>
__global__ __launch_bounds__(256) void k_mmfma(const unsigned short* __restrict__ zin,
                                               const float* __restrict__ W, const float* __restrict__ bias,
                                               const float* __restrict__ dinv,
                                               unsigned short* __restrict__ outp, int nrows) {
    __shared__ __align__(16) unsigned short Wt[128 * (K + 8)];
    __shared__ __align__(16) unsigned short At[32 * (K + 8)];
    int t = threadIdx.x;
    int base = blockIdx.x * 32;

#pragma unroll
    for (int i = 0; i < K * 128 / 256; ++i) {
        int idx = i * 256 + t;
        int k = idx >> 7, n = idx & 127;
        Wt[n * (K + 8) + k] = f2bf(W[idx]);
    }
    {
        int r = t >> 3, cb = (t & 7) * (K / 8);
        long grow = base + r;
#pragma unroll
        for (int j = 0; j < K / 32; ++j) {
            ushort4 u = make_ushort4(0, 0, 0, 0);
            if (grow < nrows) u = *(const ushort4*)&zin[grow * K + cb + j * 4];
            *(ushort4*)&At[r * (K + 8) + cb + j * 4] = u;
        }
    }
    __syncthreads();

    int w = t >> 6, lane = t & 63;
    int wm = w & 1, wn = w >> 1;
    int m = lane & 15, q = lane >> 4;
    v4f acc[4] = {};
    const unsigned short* Ap = &At[(wm * 16 + m) * (K + 8) + q * 8];
    const unsigned short* Bp = &Wt[(wn * 64 + m) * (K + 8) + q * 8];
    const int rstep = 16 * (K + 8);
#pragma unroll
    for (int ks = 0; ks < K / 32; ++ks) {
        v8s a = *(const v8s*)(Ap + ks * 32);
        v8s b0 = *(const v8s*)(Bp + 0 * rstep + ks * 32);
        v8s b1 = *(const v8s*)(Bp + 1 * rstep + ks * 32);
        v8s b2 = *(const v8s*)(Bp + 2 * rstep + ks * 32);
        v8s b3 = *(const v8s*)(Bp + 3 * rstep + ks * 32);
        acc[0] = __builtin_amdgcn_mfma_f32_16x16x32_bf16(a, b0, acc[0], 0, 0, 0);
        acc[1] = __builtin_amdgcn_mfma_f32_16x16x32_bf16(a, b1, acc[1], 0, 0, 0);
        acc[2] = __builtin_amdgcn_mfma_f32_16x16x32_bf16(a, b2, acc[2], 0, 0, 0);
        acc[3] = __builtin_amdgcn_mfma_f32_16x16x32_bf16(a, b3, acc[3], 0, 0, 0);
    }

    int col0 = wn * 64 + m;
    int rbase = base + wm * 16 + q * 4;
    float dv[4];
#pragma unroll
    for (int rg = 0; rg < 4; ++rg)
        dv[rg] = SCALE ? ((rbase + rg < nrows) ? dinv[rbase + rg] : 1.f) : 1.f;
#pragma unroll
    for (int nt = 0; nt < 4; ++nt) {
        float bc = bias[col0 + nt * 16];
#pragma unroll
        for (int rg = 0; rg < 4; ++rg) {
            int row = rbase + rg;
            if (row < nrows) {
                float o = fmaxf(acc[nt][rg] + bc, 0.f);
                outp[(long)row * 128 + col0 + nt * 16] = f2bf(o * dv[rg]);
            }
        }
    }
}

// ---------------- segment mean pool (batch sorted), bf16 input ----------------
__global__ __launch_bounds__(128) void k_pool(const unsigned short* __restrict__ y, const int* __restrict__ batch,
                                              float* __restrict__ emb_sum, float* __restrict__ cnt, int g) {
    int f = threadIdx.x;
    int start = blockIdx.x * 64;
    int end = min(start + 64, Nn);
    if (start >= Nn) return;
    float acc = 0.f;
    int cacc = 0;
    int cur = batch[start];
    for (int i = start; i < end; ++i) {
        int b = batch[i];
        if (b != cur) {
            atomicAdd(&emb_sum[(g * Bq + cur) * Hn + f], acc);
            if (f == 0) atomicAdd(&cnt[g * Bq + cur], (float)cacc);
            acc = 0.f; cacc = 0; cur = b;
        }
        acc += bf2f(y[(long)i * Hn + f]);
        cacc++;
    }
    atomicAdd(&emb_sum[(g * Bq + cur) * Hn + f], acc);
    if (f == 0) atomicAdd(&cnt[g * Bq + cur], (float)cacc);
}

// ---------------- whole MHA: one block per batch element b ----------------
__global__ __launch_bounds__(128) void k_attn(const float* __restrict__ emb_sum, const float* __restrict__ cnt,
                                              const float* __restrict__ ipw, const float* __restrict__ ipb,
                                              const float* __restrict__ opw, const float* __restrict__ opb,
                                              float* __restrict__ pooled) {
    int b = blockIdx.x;
    int f = threadIdx.x;
    __shared__ float es[4][128], qs[4][128], ks[4][128], vs[4][128], sc[128], cx[4][128];
#pragma unroll
    for (int g = 0; g < 4; ++g) {
        float c = cnt[g * Bq + b];
        es[g][f] = (c > 0.f) ? emb_sum[(g * Bq + b) * Hn + f] / c : 0.f;
    }
    __syncthreads();
#pragma unroll
    for (int g = 0; g < 4; ++g) {
        float q = ipb[f], k = ipb[Hn + f], v = ipb[2 * Hn + f];
        for (int j = 0; j < Hn; ++j) {
            float e = es[g][j];
            q += e * ipw[f * Hn + j];
            k += e * ipw[(Hn + f) * Hn + j];
            v += e * ipw[(2 * Hn + f) * Hn + j];
        }
        qs[g][f] = q; ks[g][f] = k; vs[g][f] = v;
    }
    __syncthreads();
    {
        int h = f >> 4, g = (f >> 2) & 3, kk = f & 3;
        float s = 0.f;
        for (int d = 0; d < 16; ++d) s += qs[g][h * 16 + d] * ks[kk][h * 16 + d];
        sc[f] = s * 0.25f;
    }
    __syncthreads();
    {
        int h = f >> 4;
#pragma unroll
        for (int g = 0; g < 4; ++g) {
            int bi = h * 16 + g * 4;
            float s0 = sc[bi], s1 = sc[bi + 1], s2 = sc[bi + 2], s3 = sc[bi + 3];
            float m = fmaxf(fmaxf(s0, s1), fmaxf(s2, s3));
            float e0 = __expf(s0 - m), e1 = __expf(s1 - m), e2 = __expf(s2 - m), e3 = __expf(s3 - m);
            float rinv = 1.f / (e0 + e1 + e2 + e3);
            cx[g][f] = (e0 * vs[0][f] + e1 * vs[1][f] + e2 * vs[2][f] + e3 * vs[3][f]) * rinv;
        }
    }
    __syncthreads();
#pragma unroll
    for (int g = 0; g < 4; ++g) {
        float a = opb[f];
        for (int j = 0; j < Hn; ++j) a += cx[g][j] * opw[f * Hn + j];
        atomicAdd(&pooled[g * Hn + f], a * (1.0f / Bq));
    }
}

// ---------------- final: out[g,n] = (pooled[g] . lin_w[n] + lin_b[n]) * 60 + 50 ----------------
__global__ __launch_bounds__(256) void k_final(const float* __restrict__ pooled, const float* __restrict__ lw,
                                               const float* __restrict__ lb, float* __restrict__ out) {
    __shared__ float ps[512];
    int t = threadIdx.x;
    ps[t] = pooled[t];
    ps[t + 256] = pooled[t + 256];
    __syncthreads();
    int wave = t >> 6, lane = t & 63;
    int n = blockIdx.x * 4 + wave;
    if (n >= NNODES) return;
    float2 w = *(const float2*)&lw[(long)n * 128 + lane * 2];
    float a0 = w.x * ps[0 * 128 + lane * 2] + w.y * ps[0 * 128 + lane * 2 + 1];
    float a1 = w.x * ps[1 * 128 + lane * 2] + w.y * ps[1 * 128 + lane * 2 + 1];
    float a2 = w.x * ps[2 * 128 + lane * 2] + w.y * ps[2 * 128 + lane * 2 + 1];
    float a3 = w.x * ps[3 * 128 + lane * 2] + w.y * ps[3 * 128 + lane * 2 + 1];
#pragma unroll
    for (int off = 32; off > 0; off >>= 1) {
        a0 += __shfl_down(a0, off);
        a1 += __shfl_down(a1, off);
        a2 += __shfl_down(a2, off);
        a3 += __shfl_down(a3, off);
    }
    if (lane == 0) {
        float bn = lb[n];
        out[0 * NNODES + n] = (a0 + bn) * 60.f + 50.f;
        out[1 * NNODES + n] = (a1 + bn) * 60.f + 50.f;
        out[2 * NNODES + n] = (a2 + bn) * 60.f + 50.f;
        out[3 * NNODES + n] = (a3 + bn) * 60.f + 50.f;
    }
}

extern "C" void kernel_launch(void* const* d_in, const int* in_sizes, int n_in,
                              void* d_out, int out_size, void* d_ws, size_t ws_size,
                              hipStream_t stream) {
    const float* x   = (const float*)d_in[0];
    const int*   ei  = (const int*)d_in[1];
    const int*   bat = (const int*)d_in[2];
    const float* W1  = (const float*)d_in[3];
    const float* b1  = (const float*)d_in[4];
    const float* W2  = (const float*)d_in[5];
    const float* b2  = (const float*)d_in[6];
    const float* ipw = (const float*)d_in[7];
    const float* ipb = (const float*)d_in[8];
    const float* opw = (const float*)d_in[9];
    const float* opb = (const float*)d_in[10];
    const float* lw  = (const float*)d_in[11];
    const float* lb  = (const float*)d_in[12];
    float* out = (float*)d_out;

    // workspace carve-up (~61 MB). pairs aliases z2 (dead until layer-2 agg).
    char* p = (char*)d_ws;
    unsigned short* xbs = (unsigned short*)p;                // [N,64]  bf16    6.4 MB
    unsigned short* z1  = xbs + (size_t)Nn * 64;             // [N,64]  bf16    6.4 MB
    unsigned short* y1b = (unsigned short*)(p + 12800000);   // [N,128] bf16   12.8 MB
    unsigned short* z2  = (unsigned short*)(p + 25600000);   // [N,128] bf16   12.8 MB
    unsigned int*   pairs = (unsigned int*)(p + 25600000);   // [4][E] uint    12.8 MB (alias z2)
    unsigned short* y2b = (unsigned short*)(p + 38400000);   // [N,128] bf16   12.8 MB
    int*   degi = (int*)(p + 51200000);                      // [4][N]
    int*   off  = degi + 4 * Nn;                             // [4][N+1]
    float* dinv = (float*)(off + 4 * (Nn + 1));              // [4][N]
    int*   bsum = (int*)(dinv + 4 * Nn);                     // [4][256]
    int*   btot  = bsum + 4 * 256;                           // [4][NBK]
    int*   bbase = btot + 4 * NBK;                           // [4][NBK]
    int*   bcur  = bbase + 4 * NBK;                          // [4][NBK]
    unsigned short* srcs = (unsigned short*)(bcur + 4 * NBK);// [4][E] ushort 6.4 MB
    float* emb    = (float*)(srcs + (size_t)4 * En);         // [G,B,H]
    float* cnt    = emb + Gn * Bq * Hn;                      // [G,B]
    float* pooled = cnt + Gn * Bq;                           // [G,H]

    hipMemsetAsync(btot, 0, 4 * NBK * sizeof(int), stream);
    hipMemsetAsync(emb, 0, Gn * Bq * Hn * sizeof(float), stream);
    hipMemsetAsync(cnt, 0, Gn * Bq * sizeof(float), stream);
    hipMemsetAsync(pooled, 0, Gn * Hn * sizeof(float), stream);

    const int agGrid = (Nn + 7) / 8;                 // 6250
    const int mmGrid = (Nn + 31) / 32;               // 1563
    const int plGrid = (Nn + 63) / 64;               // 782
    const int ctGrid = (Nn * 16 + 255) / 256;        // 3125

    // CSR build: bucket totals -> bases -> bucketize pairs -> per-bucket degree
    //            -> 3-stage scan -> per-bucket LDS-cursor fill
    k_btot<<<dim3(EB, 4), 256, 0, stream>>>(ei, btot);
    k_bbase<<<4, 256, 0, stream>>>(btot, bbase, bcur);
    k_bucket<<<dim3(EB, 4), 256, 0, stream>>>(ei, bcur, pairs);
    k_degb<<<dim3(NBK, 4), 256, 0, stream>>>(pairs, bbase, btot, degi);
    k_bsum4<<<dim3(NB, 4), 256, 0, stream>>>(degi, bsum);
    k_bscan4<<<4, 256, 0, stream>>>(bsum);
    k_off4<<<dim3(NB, 4), 256, 0, stream>>>(degi, bsum, off, dinv);
    k_fillb<<<dim3(NBK, 4), 256, 0, stream>>>(pairs, bbase, btot, off, srcs);

    for (int g = 0; g < Gn; ++g) {
        const float* xg = x + (size_t)g * Nn * F_IN;
        const int* bg = bat + (size_t)g * Nn;
        const int* offg = off + g * (Nn + 1);
        const float* dinvg = dinv + g * Nn;
        const unsigned short* srcg = srcs + (size_t)g * En;

        k_cast<<<ctGrid, 256, 0, stream>>>(xg, dinvg, xbs);

        // layer 1: z1 = dinv*(sum xs + xs_self); y1s = relu(z1@W1+b1)*dinv
        k_agg1<<<agGrid, 256, 0, stream>>>(xbs, offg, srcg, dinvg, z1);
        k_mmfma<64, true><<<mmGrid, 256, 0, stream>>>(z1, W1, b1, dinvg, y1b, Nn);

        // layer 2: z2 = agg(y1b) -- NOTE pairs are dead by now, z2 aliases them
        k_agg2<<<agGrid, 256, 0, stream>>>(y1b, offg, srcg, dinvg, z2);
        k_mmfma<128, false><<<mmGrid, 256, 0, stream>>>(z2, W2, b2, dinvg, y2b, Nn);

        // pool
        k_pool<<<plGrid, 128, 0, stream>>>(y2b, bg, emb, cnt, g);
    }

    k_attn<<<Bq, 128, 0, stream>>>(emb, cnt, ipw, ipb, opw, opb, pooled);
    k_final<<<(NNODES + 3) / 4, 256, 0, stream>>>(pooled, lw, lb, out);
}

// Round 9
// 611.551 us; speedup vs baseline: 3.4430x; 1.2537x over previous
//
#include <hip/hip_runtime.h>

#define Gn 4
#define Nn 50000
#define En 800000
#define Bq 32
#define F_IN 64
#define Hn 128
#define NNODES 50000
#define NBK 196     // dest buckets per graph (dest >> 8), 256 nodes each
#define EB 98       // edge chunks per graph (8192 edges each)

using v8s = __attribute__((ext_vector_type(8))) short;
using v4f = __attribute__((ext_vector_type(4))) float;

// ---- bf16 helpers (RNE) ----
__device__ __forceinline__ float bf2f(unsigned short u) {
    unsigned int x = ((unsigned int)u) << 16;
    float f; __builtin_memcpy(&f, &x, 4); return f;
}
__device__ __forceinline__ unsigned short f2bf(float f) {
    unsigned int x; __builtin_memcpy(&x, &f, 4);
    x = (x + 0x7fffu + ((x >> 16) & 1u)) >> 16;
    return (unsigned short)x;
}

// ---------------- phase 1: coarse bucket totals (bucket = dest>>8) ----------------
__global__ __launch_bounds__(256) void k_btot(const int* __restrict__ ei, int* __restrict__ btot) {
    __shared__ int h[NBK];
    int g = blockIdx.y;
    const int* col = ei + (size_t)g * 2 * En + En;
    for (int i = threadIdx.x; i < NBK; i += 256) h[i] = 0;
    __syncthreads();
    int e0 = blockIdx.x * 8192, e1 = min(e0 + 8192, En);
    for (int i = e0 / 4 + threadIdx.x; i < e1 / 4; i += 256) {
        int4 c = ((const int4*)col)[i];
        atomicAdd(&h[c.x >> 8], 1);
        atomicAdd(&h[c.y >> 8], 1);
        atomicAdd(&h[c.z >> 8], 1);
        atomicAdd(&h[c.w >> 8], 1);
    }
    __syncthreads();
    for (int i = threadIdx.x; i < NBK; i += 256)
        if (h[i]) atomicAdd(&btot[g * NBK + i], h[i]);
}

// ---------------- phase 2: scan bucket totals -> bases + global cursors ----------------
__global__ __launch_bounds__(256) void k_bbase(const int* __restrict__ btot, int* __restrict__ bbase,
                                               int* __restrict__ bcur) {
    __shared__ int s[256];
    int g = blockIdx.x, t = threadIdx.x;
    int v = (t < NBK) ? btot[g * NBK + t] : 0;
    s[t] = v;
    __syncthreads();
    for (int d = 1; d < 256; d <<= 1) {
        int u = (t >= d) ? s[t - d] : 0;
        __syncthreads();
        s[t] += u;
        __syncthreads();
    }
    if (t < NBK) { int b = s[t] - v; bbase[g * NBK + t] = b; bcur[g * NBK + t] = b; }
}

// ---------------- phase 3: bucketize edges into packed pairs (r<<16|c) ----------------
__global__ __launch_bounds__(256) void k_bucket(const int* __restrict__ ei, int* __restrict__ bcur,
                                                unsigned int* __restrict__ pairs) {
    __shared__ int h[NBK];
    __shared__ int gbase[NBK];
    int g = blockIdx.y;
    const int* row = ei + (size_t)g * 2 * En;
    const int* col = row + En;
    unsigned int* pg = pairs + (size_t)g * En;
    for (int i = threadIdx.x; i < NBK; i += 256) h[i] = 0;
    __syncthreads();
    int e0 = blockIdx.x * 8192, e1 = min(e0 + 8192, En);
    for (int i = e0 / 4 + threadIdx.x; i < e1 / 4; i += 256) {
        int4 c = ((const int4*)col)[i];
        atomicAdd(&h[c.x >> 8], 1);
        atomicAdd(&h[c.y >> 8], 1);
        atomicAdd(&h[c.z >> 8], 1);
        atomicAdd(&h[c.w >> 8], 1);
    }
    __syncthreads();
    for (int i = threadIdx.x; i < NBK; i += 256) {
        int cnt = h[i];
        gbase[i] = cnt ? atomicAdd(&bcur[g * NBK + i], cnt) : 0;
        h[i] = 0;  // becomes local cursor
    }
    __syncthreads();
    for (int i = e0 / 4 + threadIdx.x; i < e1 / 4; i += 256) {
        int4 c = ((const int4*)col)[i];
        int4 r = ((const int4*)row)[i];
        int p;
        p = gbase[c.x >> 8] + atomicAdd(&h[c.x >> 8], 1); pg[p] = ((unsigned)r.x << 16) | (unsigned)c.x;
        p = gbase[c.y >> 8] + atomicAdd(&h[c.y >> 8], 1); pg[p] = ((unsigned)r.y << 16) | (unsigned)c.y;
        p = gbase[c.z >> 8] + atomicAdd(&h[c.z >> 8], 1); pg[p] = ((unsigned)r.z << 16) | (unsigned)c.z;
        p = gbase[c.w >> 8] + atomicAdd(&h[c.w >> 8], 1); pg[p] = ((unsigned)r.w << 16) | (unsigned)c.w;
    }
}

// ---------------- phase 4 (fused): per-bucket count + scan -> off/dinv, then LDS-cursor fill ----------------
__global__ __launch_bounds__(256) void k_fillb2(const unsigned int* __restrict__ pairs,
                                                const int* __restrict__ bbase, const int* __restrict__ btot,
                                                int* __restrict__ off, float* __restrict__ dinv,
                                                unsigned short* __restrict__ srcs) {
    __shared__ int h[256], sc[256], curL[256];
    int g = blockIdx.y, b = blockIdx.x, t = threadIdx.x;
    int beg = bbase[g * NBK + b], cnt = btot[g * NBK + b];
    const unsigned int* pg = pairs + (size_t)g * En + beg;
    unsigned short* sg = srcs + (size_t)g * En;
    h[t] = 0;
    __syncthreads();
    for (int i = t; i < cnt; i += 256) atomicAdd(&h[pg[i] & 255], 1);
    __syncthreads();
    int d = h[t];
    sc[t] = d;
    __syncthreads();
    for (int dd = 1; dd < 256; dd <<= 1) {
        int u = (t >= dd) ? sc[t - dd] : 0;
        __syncthreads();
        sc[t] += u;
        __syncthreads();
    }
    int myoff = beg + sc[t] - d;  // exclusive
    int node = b * 256 + t;
    if (node < Nn) {
        off[g * (Nn + 1) + node] = myoff;
        dinv[g * Nn + node] = rsqrtf((float)d + 1.0f);
    }
    if (b == NBK - 1 && t == 255) off[g * (Nn + 1) + Nn] = beg + sc[255];
    curL[t] = myoff;
    __syncthreads();
    for (int i = t; i < cnt; i += 256) {
        unsigned int pr = pg[i];
        int pos = atomicAdd(&curL[pr & 255], 1);
        sg[pos] = (unsigned short)(pr >> 16);
    }
}

// ---------------- cast + pre-scale: xbs = bf16(x * dinv), all graphs ----------------
__global__ __launch_bounds__(256) void k_cast(const float* __restrict__ x, const float* __restrict__ dinv,
                                              unsigned short* __restrict__ xbs) {
    int g = blockIdx.y;
    int i = blockIdx.x * 256 + threadIdx.x;  // float4 index within graph
    if (i >= Nn * 16) return;
    float dc = dinv[g * Nn + (i >> 4)];
    float4 v = *(const float4*)&x[(size_t)g * Nn * 64 + i * 4];
    ushort4 u = make_ushort4(f2bf(v.x * dc), f2bf(v.y * dc), f2bf(v.z * dc), f2bf(v.w * dc));
    *(ushort4*)&xbs[(size_t)g * Nn * 64 + i * 4] = u;
}

// ---------------- agg 64-feat, all graphs ----------------
__global__ __launch_bounds__(256) void k_agg1(const unsigned short* __restrict__ xs_, const int* __restrict__ off_,
                                              const unsigned short* __restrict__ srcs_,
                                              const float* __restrict__ dinv_, unsigned short* __restrict__ z1_) {
    int g = blockIdx.y;
    const unsigned short* xs = xs_ + (size_t)g * Nn * 64;
    const int* off = off_ + g * (Nn + 1);
    const unsigned short* srcs = srcs_ + (size_t)g * En;
    unsigned short* z1 = z1_ + (size_t)g * Nn * 64;
    int node = blockIdx.x * 8 + (threadIdx.x >> 5);
    int lane = threadIdx.x & 31;
    int f2 = lane << 1;
    int beg = off[node], end = off[node + 1];
    ushort2 own = *(const ushort2*)&xs[(long)node * 64 + f2];
    float ax = bf2f(own.x), ay = bf2f(own.y);
    for (int e = beg; e < end; e += 32) {
        int k = min(32, end - e);
        int sid = 0;
        if (lane < k) sid = srcs[e + lane];
        for (int j = 0; j < k; ++j) {
            int s = __shfl(sid, j, 32);
            ushort2 u = *(const ushort2*)&xs[(long)s * 64 + f2];
            ax += bf2f(u.x);
            ay += bf2f(u.y);
        }
    }
    float dc = dinv_[g * Nn + node];
    *(ushort2*)&z1[(long)node * 64 + f2] = make_ushort2(f2bf(ax * dc), f2bf(ay * dc));
}

// ---------------- agg 128-feat, all graphs ----------------
__global__ __launch_bounds__(256) void k_agg2(const unsigned short* __restrict__ h_, const int* __restrict__ off_,
                                              const unsigned short* __restrict__ srcs_,
                                              const float* __restrict__ dinv_, unsigned short* __restrict__ z2_) {
    int g = blockIdx.y;
    const unsigned short* h = h_ + (size_t)g * Nn * 128;
    const int* off = off_ + g * (Nn + 1);
    const unsigned short* srcs = srcs_ + (size_t)g * En;
    unsigned short* z2 = z2_ + (size_t)g * Nn * 128;
    int node = blockIdx.x * 8 + (threadIdx.x >> 5);
    int lane = threadIdx.x & 31;
    int f4 = lane << 2;
    int beg = off[node], end = off[node + 1];
    ushort4 own = *(const ushort4*)&h[(long)node * 128 + f4];
    float a0 = bf2f(own.x), a1 = bf2f(own.y), a2 = bf2f(own.z), a3 = bf2f(own.w);
    for (int e = beg; e < end; e += 32) {
        int k = min(32, end - e);
        int sid = 0;
        if (lane < k) sid = srcs[e + lane];
        for (int j = 0; j < k; ++j) {
            int s = __shfl(sid, j, 32);
            ushort4 u = *(const ushort4*)&h[(long)s * 128 + f4];
            a0 += bf2f(u.x);
            a1 += bf2f(u.y);
            a2 += bf2f(u.z);
            a3 += bf2f(u.w);
        }
    }
    float dc = dinv_[g * Nn + node];
    *(ushort4*)&z2[(long)node * 128 + f4] =
        make_ushort4(f2bf(a0 * dc), f2bf(a1 * dc), f2bf(a2 * dc), f2bf(a3 * dc));
}

// ---------------- MFMA mm, all graphs: out = relu(zin@W + b) [* dinv if SCALE] ----------------
template <int K, bool SCALE>
__global__ __launch_bounds__(256) void k_mmfma(const unsigned short* __restrict__ zin_,
                                               const float* __restrict__ W, const float* __restrict__ bias,
                                               const float* __restrict__ dinv_,
                                               unsigned short* __restrict__ outp_) {
    __shared__ __align__(16) unsigned short Wt[128 * (K + 8)];
    __shared__ __align__(16) unsigned short At[32 * (K + 8)];
    int g = blockIdx.y;
    const unsigned short* zin = zin_ + (size_t)g * Nn * K;
    const float* dinv = dinv_ + g * Nn;
    unsigned short* outp = outp_ + (size_t)g * Nn * 128;
    int t = threadIdx.x;
    int base = blockIdx.x * 32;

#pragma unroll
    for (int i = 0; i < K * 128 / 256; ++i) {
        int idx = i * 256 + t;
        int k = idx >> 7, n = idx & 127;
        Wt[n * (K + 8) + k] = f2bf(W[idx]);
    }
    {
        int r = t >> 3, cb = (t & 7) * (K / 8);
        long grow = base + r;
#pragma unroll
        for (int j = 0; j < K / 32; ++j) {
            ushort4 u = make_ushort4(0, 0, 0, 0);
            if (grow < Nn) u = *(const ushort4*)&zin[grow * K + cb + j * 4];
            *(ushort4*)&At[r * (K + 8) + cb + j * 4] = u;
        }
    }
    __syncthreads();

    int w = t >> 6, lane = t & 63;
    int wm = w & 1, wn = w >> 1;
    int m = lane & 15, q = lane >> 4;
    v4f acc[4] = {};
    const unsigned short* Ap = &At[(wm * 16 + m) * (K + 8) + q * 8];
    const unsigned short* Bp = &Wt[(wn * 64 + m) * (K + 8) + q * 8];
    const int rstep = 16 * (K + 8);
#pragma unroll
    for (int ks = 0; ks < K / 32; ++ks) {
        v8s a = *(const v8s*)(Ap + ks * 32);
        v8s b0 = *(const v8s*)(Bp + 0 * rstep + ks * 32);
        v8s b1 = *(const v8s*)(Bp + 1 * rstep + ks * 32);
        v8s b2 = *(const v8s*)(Bp + 2 * rstep + ks * 32);
        v8s b3 = *(const v8s*)(Bp + 3 * rstep + ks * 32);
        acc[0] = __builtin_amdgcn_mfma_f32_16x16x32_bf16(a, b0, acc[0], 0, 0, 0);
        acc[1] = __builtin_amdgcn_mfma_f32_16x16x32_bf16(a, b1, acc[1], 0, 0, 0);
        acc[2] = __builtin_amdgcn_mfma_f32_16x16x32_bf16(a, b2, acc[2], 0, 0, 0);
        acc[3] = __builtin_amdgcn_mfma_f32_16x16x32_bf16(a, b3, acc[3], 0, 0, 0);
    }

    int col0 = wn * 64 + m;
    int rbase = base + wm * 16 + q * 4;
    float dv[4];
#pragma unroll
    for (int rg = 0; rg < 4; ++rg)
        dv[rg] = SCALE ? ((rbase + rg < Nn) ? dinv[rbase + rg] : 1.f) : 1.f;
#pragma unroll
    for (int nt = 0; nt < 4; ++nt) {
        float bc = bias[col0 + nt * 16];
#pragma unroll
        for (int rg = 0; rg < 4; ++rg) {
            int row = rbase + rg;
            if (row < Nn) {
                float o = fmaxf(acc[nt][rg] + bc, 0.f);
                outp[(long)row * 128 + col0 + nt * 16] = f2bf(o * dv[rg]);
            }
        }
    }
}

// ---------------- segment mean pool (batch sorted), all graphs ----------------
__global__ __launch_bounds__(128) void k_pool(const unsigned short* __restrict__ y_, const int* __restrict__ bat,
                                              float* __restrict__ emb_sum, float* __restrict__ cnt) {
    int g = blockIdx.y;
    const unsigned short* y = y_ + (size_t)g * Nn * 128;
    const int* batch = bat + (size_t)g * Nn;
    int f = threadIdx.x;
    int start = blockIdx.x * 64;
    int end = min(start + 64, Nn);
    if (start >= Nn) return;
    float acc = 0.f;
    int cacc = 0;
    int cur = batch[start];
    for (int i = start; i < end; ++i) {
        int b = batch[i];
        if (b != cur) {
            atomicAdd(&emb_sum[(g * Bq + cur) * Hn + f], acc);
            if (f == 0) atomicAdd(&cnt[g * Bq + cur], (float)cacc);
            acc = 0.f; cacc = 0; cur = b;
        }
        acc += bf2f(y[(long)i * Hn + f]);
        cacc++;
    }
    atomicAdd(&emb_sum[(g * Bq + cur) * Hn + f], acc);
    if (f == 0) atomicAdd(&cnt[g * Bq + cur], (float)cacc);
}

// ---------------- whole MHA: one block per batch element b ----------------
__global__ __launch_bounds__(128) void k_attn(const float* __restrict__ emb_sum, const float* __restrict__ cnt,
                                              const float* __restrict__ ipw, const float* __restrict__ ipb,
                                              const float* __restrict__ opw, const float* __restrict__ opb,
                                              float* __restrict__ pooled) {
    int b = blockIdx.x;
    int f = threadIdx.x;
    __shared__ float es[4][128], qs[4][128], ks[4][128], vs[4][128], sc[128], cx[4][128];
#pragma unroll
    for (int g = 0; g < 4; ++g) {
        float c = cnt[g * Bq + b];
        es[g][f] = (c > 0.f) ? emb_sum[(g * Bq + b) * Hn + f] / c : 0.f;
    }
    __syncthreads();
#pragma unroll
    for (int g = 0; g < 4; ++g) {
        float q = ipb[f], k = ipb[Hn + f], v = ipb[2 * Hn + f];
        for (int j = 0; j < Hn; ++j) {
            float e = es[g][j];
            q += e * ipw[f * Hn + j];
            k += e * ipw[(Hn + f) * Hn + j];
            v += e * ipw[(2 * Hn + f) * Hn + j];
        }
        qs[g][f] = q; ks[g][f] = k; vs[g][f] = v;
    }
    __syncthreads();
    {
        int h = f >> 4, g = (f >> 2) & 3, kk = f & 3;
        float s = 0.f;
        for (int d = 0; d < 16; ++d) s += qs[g][h * 16 + d] * ks[kk][h * 16 + d];
        sc[f] = s * 0.25f;
    }
    __syncthreads();
    {
        int h = f >> 4;
#pragma unroll
        for (int g = 0; g < 4; ++g) {
            int bi = h * 16 + g * 4;
            float s0 = sc[bi], s1 = sc[bi + 1], s2 = sc[bi + 2], s3 = sc[bi + 3];
            float m = fmaxf(fmaxf(s0, s1), fmaxf(s2, s3));
            float e0 = __expf(s0 - m), e1 = __expf(s1 - m), e2 = __expf(s2 - m), e3 = __expf(s3 - m);
            float rinv = 1.f / (e0 + e1 + e2 + e3);
            cx[g][f] = (e0 * vs[0][f] + e1 * vs[1][f] + e2 * vs[2][f] + e3 * vs[3][f]) * rinv;
        }
    }
    __syncthreads();
#pragma unroll
    for (int g = 0; g < 4; ++g) {
        float a = opb[f];
        for (int j = 0; j < Hn; ++j) a += cx[g][j] * opw[f * Hn + j];
        atomicAdd(&pooled[g * Hn + f], a * (1.0f / Bq));
    }
}

// ---------------- final: out[g,n] = (pooled[g] . lin_w[n] + lin_b[n]) * 60 + 50 ----------------
__global__ __launch_bounds__(256) void k_final(const float* __restrict__ pooled, const float* __restrict__ lw,
                                               const float* __restrict__ lb, float* __restrict__ out) {
    __shared__ float ps[512];
    int t = threadIdx.x;
    ps[t] = pooled[t];
    ps[t + 256] = pooled[t + 256];
    __syncthreads();
    int wave = t >> 6, lane = t & 63;
    int n = blockIdx.x * 4 + wave;
    if (n >= NNODES) return;
    float2 w = *(const float2*)&lw[(long)n * 128 + lane * 2];
    float a0 = w.x * ps[0 * 128 + lane * 2] + w.y * ps[0 * 128 + lane * 2 + 1];
    float a1 = w.x * ps[1 * 128 + lane * 2] + w.y * ps[1 * 128 + lane * 2 + 1];
    float a2 = w.x * ps[2 * 128 + lane * 2] + w.y * ps[2 * 128 + lane * 2 + 1];
    float a3 = w.x * ps[3 * 128 + lane * 2] + w.y * ps[3 * 128 + lane * 2 + 1];
#pragma unroll
    for (int off = 32; off > 0; off >>= 1) {
        a0 += __shfl_down(a0, off);
        a1 += __shfl_down(a1, off);
        a2 += __shfl_down(a2, off);
        a3 += __shfl_down(a3, off);
    }
    if (lane == 0) {
        float bn = lb[n];
        out[0 * NNODES + n] = (a0 + bn) * 60.f + 50.f;
        out[1 * NNODES + n] = (a1 + bn) * 60.f + 50.f;
        out[2 * NNODES + n] = (a2 + bn) * 60.f + 50.f;
        out[3 * NNODES + n] = (a3 + bn) * 60.f + 50.f;
    }
}

extern "C" void kernel_launch(void* const* d_in, const int* in_sizes, int n_in,
                              void* d_out, int out_size, void* d_ws, size_t ws_size,
                              hipStream_t stream) {
    const float* x   = (const float*)d_in[0];
    const int*   ei  = (const int*)d_in[1];
    const int*   bat = (const int*)d_in[2];
    const float* W1  = (const float*)d_in[3];
    const float* b1  = (const float*)d_in[4];
    const float* W2  = (const float*)d_in[5];
    const float* b2  = (const float*)d_in[6];
    const float* ipw = (const float*)d_in[7];
    const float* ipb = (const float*)d_in[8];
    const float* opw = (const float*)d_in[9];
    const float* opb = (const float*)d_in[10];
    const float* lw  = (const float*)d_in[11];
    const float* lb  = (const float*)d_in[12];
    float* out = (float*)d_out;

    // workspace carve-up (~214 MB; ws is 256 MiB per harness poison size)
    char* p = (char*)d_ws;
    unsigned short* xbs = (unsigned short*)p;                 // [4][N,64]  bf16  25.6 MB
    unsigned short* z1  = (unsigned short*)(p + 25600000);    // [4][N,64]  bf16  25.6 MB
    unsigned short* y1b = (unsigned short*)(p + 51200000);    // [4][N,128] bf16  51.2 MB
    unsigned short* z2  = (unsigned short*)(p + 102400000);   // [4][N,128] bf16  51.2 MB
    unsigned int*   pairs = (unsigned int*)(p + 102400000);   // [4][E] uint 12.8 MB (alias z2; dead before agg2)
    unsigned short* y2b = (unsigned short*)(p + 153600000);   // [4][N,128] bf16  51.2 MB
    char* meta = p + 204800000;
    int*   off  = (int*)meta;                                 // [4][N+1]
    float* dinv = (float*)(off + 4 * (Nn + 1));               // [4][N]
    int*   btot  = (int*)(dinv + 4 * Nn);                     // [4][NBK]
    int*   bbase = btot + 4 * NBK;                            // [4][NBK]
    int*   bcur  = bbase + 4 * NBK;                           // [4][NBK]
    unsigned short* srcs = (unsigned short*)(bcur + 4 * NBK); // [4][E] ushort 6.4 MB
    float* emb    = (float*)(srcs + (size_t)4 * En);          // [G,B,H]
    float* cnt    = emb + Gn * Bq * Hn;                       // [G,B]
    float* pooled = cnt + Gn * Bq;                            // [G,H]

    hipMemsetAsync(btot, 0, 4 * NBK * sizeof(int), stream);
    hipMemsetAsync(emb, 0, Gn * Bq * Hn * sizeof(float), stream);
    hipMemsetAsync(cnt, 0, Gn * Bq * sizeof(float), stream);
    hipMemsetAsync(pooled, 0, Gn * Hn * sizeof(float), stream);

    const int agGrid = (Nn + 7) / 8;                 // 6250
    const int mmGrid = (Nn + 31) / 32;               // 1563
    const int plGrid = (Nn + 63) / 64;               // 782
    const int ctGrid = (Nn * 16 + 255) / 256;        // 3125

    // CSR build: totals -> bases -> bucketize -> fused (count+scan+off/dinv+fill)
    k_btot<<<dim3(EB, Gn), 256, 0, stream>>>(ei, btot);
    k_bbase<<<Gn, 256, 0, stream>>>(btot, bbase, bcur);
    k_bucket<<<dim3(EB, Gn), 256, 0, stream>>>(ei, bcur, pairs);
    k_fillb2<<<dim3(NBK, Gn), 256, 0, stream>>>(pairs, bbase, btot, off, dinv, srcs);

    // GCN layers, all graphs per launch
    k_cast<<<dim3(ctGrid, Gn), 256, 0, stream>>>(x, dinv, xbs);
    k_agg1<<<dim3(agGrid, Gn), 256, 0, stream>>>(xbs, off, srcs, dinv, z1);
    k_mmfma<64, true><<<dim3(mmGrid, Gn), 256, 0, stream>>>(z1, W1, b1, dinv, y1b);
    k_agg2<<<dim3(agGrid, Gn), 256, 0, stream>>>(y1b, off, srcs, dinv, z2);
    k_mmfma<128, false><<<dim3(mmGrid, Gn), 256, 0, stream>>>(z2, W2, b2, dinv, y2b);
    k_pool<<<dim3(plGrid, Gn), 128, 0, stream>>>(y2b, bat, emb, cnt);

    k_attn<<<Bq, 128, 0, stream>>>(emb, cnt, ipw, ipb, opw, opb, pooled);
    k_final<<<(NNODES + 3) / 4, 256, 0, stream>>>(pooled, lw, lb, out);
}

// Round 10
// 561.865 us; speedup vs baseline: 3.7474x; 1.0884x over previous
//
#include <hip/hip_runtime.h>

#define Gn 4
#define Nn 50000
#define En 800000
#define Bq 32
#define F_IN 64
#define Hn 128
#define NNODES 50000
#define NBK 196     // dest buckets per graph (dest >> 8), 256 nodes each
#define EB 98       // edge chunks per graph (8192 edges each)

using v8s = __attribute__((ext_vector_type(8))) short;
using v4f = __attribute__((ext_vector_type(4))) float;

// ---- bf16 helpers (RNE) ----
__device__ __forceinline__ float bf2f(unsigned short u) {
    unsigned int x = ((unsigned int)u) << 16;
    float f; __builtin_memcpy(&f, &x, 4); return f;
}
__device__ __forceinline__ unsigned short f2bf(float f) {
    unsigned int x; __builtin_memcpy(&x, &f, 4);
    x = (x + 0x7fffu + ((x >> 16) & 1u)) >> 16;
    return (unsigned short)x;
}

// ---------------- phase 1: coarse bucket totals (bucket = dest>>8) ----------------
__global__ __launch_bounds__(256) void k_btot(const int* __restrict__ ei, int* __restrict__ btot) {
    __shared__ int h[NBK];
    int g = blockIdx.y;
    const int* col = ei + (size_t)g * 2 * En + En;
    for (int i = threadIdx.x; i < NBK; i += 256) h[i] = 0;
    __syncthreads();
    int e0 = blockIdx.x * 8192, e1 = min(e0 + 8192, En);
    for (int i = e0 / 4 + threadIdx.x; i < e1 / 4; i += 256) {
        int4 c = ((const int4*)col)[i];
        atomicAdd(&h[c.x >> 8], 1);
        atomicAdd(&h[c.y >> 8], 1);
        atomicAdd(&h[c.z >> 8], 1);
        atomicAdd(&h[c.w >> 8], 1);
    }
    __syncthreads();
    for (int i = threadIdx.x; i < NBK; i += 256)
        if (h[i]) atomicAdd(&btot[g * NBK + i], h[i]);
}

// ---------------- phase 2: scan bucket totals -> bases + global cursors ----------------
__global__ __launch_bounds__(256) void k_bbase(const int* __restrict__ btot, int* __restrict__ bbase,
                                               int* __restrict__ bcur) {
    __shared__ int s[256];
    int g = blockIdx.x, t = threadIdx.x;
    int v = (t < NBK) ? btot[g * NBK + t] : 0;
    s[t] = v;
    __syncthreads();
    for (int d = 1; d < 256; d <<= 1) {
        int u = (t >= d) ? s[t - d] : 0;
        __syncthreads();
        s[t] += u;
        __syncthreads();
    }
    if (t < NBK) { int b = s[t] - v; bbase[g * NBK + t] = b; bcur[g * NBK + t] = b; }
}

// ---------------- phase 3: bucketize edges into packed pairs (r<<16|c) ----------------
__global__ __launch_bounds__(256) void k_bucket(const int* __restrict__ ei, int* __restrict__ bcur,
                                                unsigned int* __restrict__ pairs) {
    __shared__ int h[NBK];
    __shared__ int gbase[NBK];
    int g = blockIdx.y;
    const int* row = ei + (size_t)g * 2 * En;
    const int* col = row + En;
    unsigned int* pg = pairs + (size_t)g * En;
    for (int i = threadIdx.x; i < NBK; i += 256) h[i] = 0;
    __syncthreads();
    int e0 = blockIdx.x * 8192, e1 = min(e0 + 8192, En);
    for (int i = e0 / 4 + threadIdx.x; i < e1 / 4; i += 256) {
        int4 c = ((const int4*)col)[i];
        atomicAdd(&h[c.x >> 8], 1);
        atomicAdd(&h[c.y >> 8], 1);
        atomicAdd(&h[c.z >> 8], 1);
        atomicAdd(&h[c.w >> 8], 1);
    }
    __syncthreads();
    for (int i = threadIdx.x; i < NBK; i += 256) {
        int cnt = h[i];
        gbase[i] = cnt ? atomicAdd(&bcur[g * NBK + i], cnt) : 0;
        h[i] = 0;  // becomes local cursor
    }
    __syncthreads();
    for (int i = e0 / 4 + threadIdx.x; i < e1 / 4; i += 256) {
        int4 c = ((const int4*)col)[i];
        int4 r = ((const int4*)row)[i];
        int p;
        p = gbase[c.x >> 8] + atomicAdd(&h[c.x >> 8], 1); pg[p] = ((unsigned)r.x << 16) | (unsigned)c.x;
        p = gbase[c.y >> 8] + atomicAdd(&h[c.y >> 8], 1); pg[p] = ((unsigned)r.y << 16) | (unsigned)c.y;
        p = gbase[c.z >> 8] + atomicAdd(&h[c.z >> 8], 1); pg[p] = ((unsigned)r.z << 16) | (unsigned)c.z;
        p = gbase[c.w >> 8] + atomicAdd(&h[c.w >> 8], 1); pg[p] = ((unsigned)r.w << 16) | (unsigned)c.w;
    }
}

// ---------------- phase 4 (fused): per-bucket count + scan -> off/dinv, then LDS-cursor fill ----------------
__global__ __launch_bounds__(256) void k_fillb2(const unsigned int* __restrict__ pairs,
                                                const int* __restrict__ bbase, const int* __restrict__ btot,
                                                int* __restrict__ off, float* __restrict__ dinv,
                                                unsigned short* __restrict__ srcs) {
    __shared__ int h[256], sc[256], curL[256];
    int g = blockIdx.y, b = blockIdx.x, t = threadIdx.x;
    int beg = bbase[g * NBK + b], cnt = btot[g * NBK + b];
    const unsigned int* pg = pairs + (size_t)g * En + beg;
    unsigned short* sg = srcs + (size_t)g * En;
    h[t] = 0;
    __syncthreads();
    for (int i = t; i < cnt; i += 256) atomicAdd(&h[pg[i] & 255], 1);
    __syncthreads();
    int d = h[t];
    sc[t] = d;
    __syncthreads();
    for (int dd = 1; dd < 256; dd <<= 1) {
        int u = (t >= dd) ? sc[t - dd] : 0;
        __syncthreads();
        sc[t] += u;
        __syncthreads();
    }
    int myoff = beg + sc[t] - d;  // exclusive
    int node = b * 256 + t;
    if (node < Nn) {
        off[g * (Nn + 1) + node] = myoff;
        dinv[g * Nn + node] = rsqrtf((float)d + 1.0f);
    }
    if (b == NBK - 1 && t == 255) off[g * (Nn + 1) + Nn] = beg + sc[255];
    curL[t] = myoff;
    __syncthreads();
    for (int i = t; i < cnt; i += 256) {
        unsigned int pr = pg[i];
        int pos = atomicAdd(&curL[pr & 255], 1);
        sg[pos] = (unsigned short)(pr >> 16);
    }
}

// ---------------- cast + pre-scale: xbs = bf16(x * dinv), all graphs ----------------
__global__ __launch_bounds__(256) void k_cast(const float* __restrict__ x, const float* __restrict__ dinv,
                                              unsigned short* __restrict__ xbs) {
    int g = blockIdx.y;
    int i = blockIdx.x * 256 + threadIdx.x;  // float4 index within graph
    if (i >= Nn * 16) return;
    float dc = dinv[g * Nn + (i >> 4)];
    float4 v = *(const float4*)&x[(size_t)g * Nn * 64 + i * 4];
    ushort4 u = make_ushort4(f2bf(v.x * dc), f2bf(v.y * dc), f2bf(v.z * dc), f2bf(v.w * dc));
    *(ushort4*)&xbs[(size_t)g * Nn * 64 + i * 4] = u;
}

// ---------------- agg 64-feat, MLP layout: 4 edge slots x 8 feature lanes per node ----------------
__global__ __launch_bounds__(256) void k_agg1(const unsigned short* __restrict__ xs_, const int* __restrict__ off_,
                                              const unsigned short* __restrict__ srcs_,
                                              const float* __restrict__ dinv_, unsigned short* __restrict__ z1_) {
    int g = blockIdx.y;
    const unsigned short* xs = xs_ + (size_t)g * Nn * 64;
    const int* off = off_ + g * (Nn + 1);
    const unsigned short* srcs = srcs_ + (size_t)g * En;
    unsigned short* z1 = z1_ + (size_t)g * Nn * 64;
    int node = blockIdx.x * 8 + (threadIdx.x >> 5);
    int lane = threadIdx.x & 31;
    int sub = lane >> 3;   // edge slot 0..3
    int fo = lane & 7;     // feature octile: feats [fo*8, fo*8+8)
    int beg = off[node], end = off[node + 1];
    float acc[8] = {};
    for (int e = beg; e < end; e += 32) {
        int sid = 0;
        if (e + lane < end) sid = srcs[e + lane];
        int kc = min(32, end - e);
        if (kc == 32) {
#pragma unroll
            for (int jj = 0; jj < 8; ++jj) {
                int s = __shfl(sid, jj * 4 + sub, 32);
                v8s u = *(const v8s*)&xs[(long)s * 64 + fo * 8];
#pragma unroll
                for (int q = 0; q < 8; ++q) acc[q] += bf2f((unsigned short)u[q]);
            }
        } else {
#pragma unroll
            for (int jj = 0; jj < 8; ++jj) {
                int j = jj * 4 + sub;
                int s = __shfl(sid, j, 32);
                if (j < kc) {
                    v8s u = *(const v8s*)&xs[(long)s * 64 + fo * 8];
#pragma unroll
                    for (int q = 0; q < 8; ++q) acc[q] += bf2f((unsigned short)u[q]);
                }
            }
        }
    }
#pragma unroll
    for (int q = 0; q < 8; ++q) {
        acc[q] += __shfl_xor(acc[q], 8, 32);
        acc[q] += __shfl_xor(acc[q], 16, 32);
    }
    if (sub == 0) {
        float dc = dinv_[g * Nn + node];
        v8s ow = *(const v8s*)&xs[(long)node * 64 + fo * 8];
        ushort4 o0, o1;
        o0.x = f2bf((acc[0] + bf2f((unsigned short)ow[0])) * dc);
        o0.y = f2bf((acc[1] + bf2f((unsigned short)ow[1])) * dc);
        o0.z = f2bf((acc[2] + bf2f((unsigned short)ow[2])) * dc);
        o0.w = f2bf((acc[3] + bf2f((unsigned short)ow[3])) * dc);
        o1.x = f2bf((acc[4] + bf2f((unsigned short)ow[4])) * dc);
        o1.y = f2bf((acc[5] + bf2f((unsigned short)ow[5])) * dc);
        o1.z = f2bf((acc[6] + bf2f((unsigned short)ow[6])) * dc);
        o1.w = f2bf((acc[7] + bf2f((unsigned short)ow[7])) * dc);
        *(ushort4*)&z1[(long)node * 64 + fo * 8] = o0;
        *(ushort4*)&z1[(long)node * 64 + fo * 8 + 4] = o1;
    }
}

// ---------------- agg 128-feat, MLP layout: 4 edge slots x 8 feature lanes (16 feats each) ----------------
__global__ __launch_bounds__(256) void k_agg2(const unsigned short* __restrict__ h_, const int* __restrict__ off_,
                                              const unsigned short* __restrict__ srcs_,
                                              const float* __restrict__ dinv_, unsigned short* __restrict__ z2_) {
    int g = blockIdx.y;
    const unsigned short* h = h_ + (size_t)g * Nn * 128;
    const int* off = off_ + g * (Nn + 1);
    const unsigned short* srcs = srcs_ + (size_t)g * En;
    unsigned short* z2 = z2_ + (size_t)g * Nn * 128;
    int node = blockIdx.x * 8 + (threadIdx.x >> 5);
    int lane = threadIdx.x & 31;
    int sub = lane >> 3;   // edge slot 0..3
    int fo = lane & 7;     // feature 16-tile: feats [fo*16, fo*16+16)
    int beg = off[node], end = off[node + 1];
    float acc[16] = {};
    for (int e = beg; e < end; e += 32) {
        int sid = 0;
        if (e + lane < end) sid = srcs[e + lane];
        int kc = min(32, end - e);
        if (kc == 32) {
#pragma unroll
            for (int jj = 0; jj < 8; ++jj) {
                int s = __shfl(sid, jj * 4 + sub, 32);
                const unsigned short* rp = &h[(long)s * 128 + fo * 16];
                v8s u0 = *(const v8s*)rp;
                v8s u1 = *(const v8s*)(rp + 8);
#pragma unroll
                for (int q = 0; q < 8; ++q) acc[q] += bf2f((unsigned short)u0[q]);
#pragma unroll
                for (int q = 0; q < 8; ++q) acc[8 + q] += bf2f((unsigned short)u1[q]);
            }
        } else {
#pragma unroll
            for (int jj = 0; jj < 8; ++jj) {
                int j = jj * 4 + sub;
                int s = __shfl(sid, j, 32);
                if (j < kc) {
                    const unsigned short* rp = &h[(long)s * 128 + fo * 16];
                    v8s u0 = *(const v8s*)rp;
                    v8s u1 = *(const v8s*)(rp + 8);
#pragma unroll
                    for (int q = 0; q < 8; ++q) acc[q] += bf2f((unsigned short)u0[q]);
#pragma unroll
                    for (int q = 0; q < 8; ++q) acc[8 + q] += bf2f((unsigned short)u1[q]);
                }
            }
        }
    }
#pragma unroll
    for (int q = 0; q < 16; ++q) {
        acc[q] += __shfl_xor(acc[q], 8, 32);
        acc[q] += __shfl_xor(acc[q], 16, 32);
    }
    if (sub == 0) {
        float dc = dinv_[g * Nn + node];
        const unsigned short* op = &h[(long)node * 128 + fo * 16];
        unsigned short* zp = &z2[(long)node * 128 + fo * 16];
#pragma unroll
        for (int q4 = 0; q4 < 4; ++q4) {
            ushort4 ow = *(const ushort4*)(op + q4 * 4);
            ushort4 o;
            o.x = f2bf((acc[q4 * 4 + 0] + bf2f(ow.x)) * dc);
            o.y = f2bf((acc[q4 * 4 + 1] + bf2f(ow.y)) * dc);
            o.z = f2bf((acc[q4 * 4 + 2] + bf2f(ow.z)) * dc);
            o.w = f2bf((acc[q4 * 4 + 3] + bf2f(ow.w)) * dc);
            *(ushort4*)(zp + q4 * 4) = o;
        }
    }
}

// ---------------- MFMA mm, all graphs: out = relu(zin@W + b) [* dinv if SCALE] ----------------
template <int K, bool SCALE>
__global__ __launch_bounds__(256) void k_mmfma(const unsigned short* __restrict__ zin_,
                                               const float* __restrict__ W, const float* __restrict__ bias,
                                               const float* __restrict__ dinv_,
                                               unsigned short* __restrict__ outp_) {
    __shared__ __align__(16) unsigned short Wt[128 * (K + 8)];
    __shared__ __align__(16) unsigned short At[32 * (K + 8)];
    int g = blockIdx.y;
    const unsigned short* zin = zin_ + (size_t)g * Nn * K;
    const float* dinv = dinv_ + g * Nn;
    unsigned short* outp = outp_ + (size_t)g * Nn * 128;
    int t = threadIdx.x;
    int base = blockIdx.x * 32;

#pragma unroll
    for (int i = 0; i < K * 128 / 256; ++i) {
        int idx = i * 256 + t;
        int k = idx >> 7, n = idx & 127;
        Wt[n * (K + 8) + k] = f2bf(W[idx]);
    }
    {
        int r = t >> 3, cb = (t & 7) * (K / 8);
        long grow = base + r;
#pragma unroll
        for (int j = 0; j < K / 32; ++j) {
            ushort4 u = make_ushort4(0, 0, 0, 0);
            if (grow < Nn) u = *(const ushort4*)&zin[grow * K + cb + j * 4];
            *(ushort4*)&At[r * (K + 8) + cb + j * 4] = u;
        }
    }
    __syncthreads();

    int w = t >> 6, lane = t & 63;
    int wm = w & 1, wn = w >> 1;
    int m = lane & 15, q = lane >> 4;
    v4f acc[4] = {};
    const unsigned short* Ap = &At[(wm * 16 + m) * (K + 8) + q * 8];
    const unsigned short* Bp = &Wt[(wn * 64 + m) * (K + 8) + q * 8];
    const int rstep = 16 * (K + 8);
#pragma unroll
    for (int ks = 0; ks < K / 32; ++ks) {
        v8s a = *(const v8s*)(Ap + ks * 32);
        v8s b0 = *(const v8s*)(Bp + 0 * rstep + ks * 32);
        v8s b1 = *(const v8s*)(Bp + 1 * rstep + ks * 32);
        v8s b2 = *(const v8s*)(Bp + 2 * rstep + ks * 32);
        v8s b3 = *(const v8s*)(Bp + 3 * rstep + ks * 32);
        acc[0] = __builtin_amdgcn_mfma_f32_16x16x32_bf16(a, b0, acc[0], 0, 0, 0);
        acc[1] = __builtin_amdgcn_mfma_f32_16x16x32_bf16(a, b1, acc[1], 0, 0, 0);
        acc[2] = __builtin_amdgcn_mfma_f32_16x16x32_bf16(a, b2, acc[2], 0, 0, 0);
        acc[3] = __builtin_amdgcn_mfma_f32_16x16x32_bf16(a, b3, acc[3], 0, 0, 0);
    }

    int col0 = wn * 64 + m;
    int rbase = base + wm * 16 + q * 4;
    float dv[4];
#pragma unroll
    for (int rg = 0; rg < 4; ++rg)
        dv[rg] = SCALE ? ((rbase + rg < Nn) ? dinv[rbase + rg] : 1.f) : 1.f;
#pragma unroll
    for (int nt = 0; nt < 4; ++nt) {
        float bc = bias[col0 + nt * 16];
#pragma unroll
        for (int rg = 0; rg < 4; ++rg) {
            int row = rbase + rg;
            if (row < Nn) {
                float o = fmaxf(acc[nt][rg] + bc, 0.f);
                outp[(long)row * 128 + col0 + nt * 16] = f2bf(o * dv[rg]);
            }
        }
    }
}

// ---------------- segment mean pool (batch sorted), all graphs ----------------
__global__ __launch_bounds__(128) void k_pool(const unsigned short* __restrict__ y_, const int* __restrict__ bat,
                                              float* __restrict__ emb_sum, float* __restrict__ cnt) {
    int g = blockIdx.y;
    const unsigned short* y = y_ + (size_t)g * Nn * 128;
    const int* batch = bat + (size_t)g * Nn;
    int f = threadIdx.x;
    int start = blockIdx.x * 64;
    int end = min(start + 64, Nn);
    if (start >= Nn) return;
    float acc = 0.f;
    int cacc = 0;
    int cur = batch[start];
    for (int i = start; i < end; ++i) {
        int b = batch[i];
        if (b != cur) {
            atomicAdd(&emb_sum[(g * Bq + cur) * Hn + f], acc);
            if (f == 0) atomicAdd(&cnt[g * Bq + cur], (float)cacc);
            acc = 0.f; cacc = 0; cur = b;
        }
        acc += bf2f(y[(long)i * Hn + f]);
        cacc++;
    }
    atomicAdd(&emb_sum[(g * Bq + cur) * Hn + f], acc);
    if (f == 0) atomicAdd(&cnt[g * Bq + cur], (float)cacc);
}

// ---------------- whole MHA: one block per batch element b ----------------
__global__ __launch_bounds__(128) void k_attn(const float* __restrict__ emb_sum, const float* __restrict__ cnt,
                                              const float* __restrict__ ipw, const float* __restrict__ ipb,
                                              const float* __restrict__ opw, const float* __restrict__ opb,
                                              float* __restrict__ pooled) {
    int b = blockIdx.x;
    int f = threadIdx.x;
    __shared__ float es[4][128], qs[4][128], ks[4][128], vs[4][128], sc[128], cx[4][128];
#pragma unroll
    for (int g = 0; g < 4; ++g) {
        float c = cnt[g * Bq + b];
        es[g][f] = (c > 0.f) ? emb_sum[(g * Bq + b) * Hn + f] / c : 0.f;
    }
    __syncthreads();
#pragma unroll
    for (int g = 0; g < 4; ++g) {
        float q = ipb[f], k = ipb[Hn + f], v = ipb[2 * Hn + f];
        for (int j = 0; j < Hn; ++j) {
            float e = es[g][j];
            q += e * ipw[f * Hn + j];
            k += e * ipw[(Hn + f) * Hn + j];
            v += e * ipw[(2 * Hn + f) * Hn + j];
        }
        qs[g][f] = q; ks[g][f] = k; vs[g][f] = v;
    }
    __syncthreads();
    {
        int h = f >> 4, g = (f >> 2) & 3, kk = f & 3;
        float s = 0.f;
        for (int d = 0; d < 16; ++d) s += qs[g][h * 16 + d] * ks[kk][h * 16 + d];
        sc[f] = s * 0.25f;
    }
    __syncthreads();
    {
        int h = f >> 4;
#pragma unroll
        for (int g = 0; g < 4; ++g) {
            int bi = h * 16 + g * 4;
            float s0 = sc[bi], s1 = sc[bi + 1], s2 = sc[bi + 2], s3 = sc[bi + 3];
            float m = fmaxf(fmaxf(s0, s1), fmaxf(s2, s3));
            float e0 = __expf(s0 - m), e1 = __expf(s1 - m), e2 = __expf(s2 - m), e3 = __expf(s3 - m);
            float rinv = 1.f / (e0 + e1 + e2 + e3);
            cx[g][f] = (e0 * vs[0][f] + e1 * vs[1][f] + e2 * vs[2][f] + e3 * vs[3][f]) * rinv;
        }
    }
    __syncthreads();
#pragma unroll
    for (int g = 0; g < 4; ++g) {
        float a = opb[f];
        for (int j = 0; j < Hn; ++j) a += cx[g][j] * opw[f * Hn + j];
        atomicAdd(&pooled[g * Hn + f], a * (1.0f / Bq));
    }
}

// ---------------- final: out[g,n] = (pooled[g] . lin_w[n] + lin_b[n]) * 60 + 50 ----------------
__global__ __launch_bounds__(256) void k_final(const float* __restrict__ pooled, const float* __restrict__ lw,
                                               const float* __restrict__ lb, float* __restrict__ out) {
    __shared__ float ps[512];
    int t = threadIdx.x;
    ps[t] = pooled[t];
    ps[t + 256] = pooled[t + 256];
    __syncthreads();
    int wave = t >> 6, lane = t & 63;
    int n = blockIdx.x * 4 + wave;
    if (n >= NNODES) return;
    float2 w = *(const float2*)&lw[(long)n * 128 + lane * 2];
    float a0 = w.x * ps[0 * 128 + lane * 2] + w.y * ps[0 * 128 + lane * 2 + 1];
    float a1 = w.x * ps[1 * 128 + lane * 2] + w.y * ps[1 * 128 + lane * 2 + 1];
    float a2 = w.x * ps[2 * 128 + lane * 2] + w.y * ps[2 * 128 + lane * 2 + 1];
    float a3 = w.x * ps[3 * 128 + lane * 2] + w.y * ps[3 * 128 + lane * 2 + 1];
#pragma unroll
    for (int off = 32; off > 0; off >>= 1) {
        a0 += __shfl_down(a0, off);
        a1 += __shfl_down(a1, off);
        a2 += __shfl_down(a2, off);
        a3 += __shfl_down(a3, off);
    }
    if (lane == 0) {
        float bn = lb[n];
        out[0 * NNODES + n] = (a0 + bn) * 60.f + 50.f;
        out[1 * NNODES + n] = (a1 + bn) * 60.f + 50.f;
        out[2 * NNODES + n] = (a2 + bn) * 60.f + 50.f;
        out[3 * NNODES + n] = (a3 + bn) * 60.f + 50.f;
    }
}

extern "C" void kernel_launch(void* const* d_in, const int* in_sizes, int n_in,
                              void* d_out, int out_size, void* d_ws, size_t ws_size,
                              hipStream_t stream) {
    const float* x   = (const float*)d_in[0];
    const int*   ei  = (const int*)d_in[1];
    const int*   bat = (const int*)d_in[2];
    const float* W1  = (const float*)d_in[3];
    const float* b1  = (const float*)d_in[4];
    const float* W2  = (const float*)d_in[5];
    const float* b2  = (const float*)d_in[6];
    const float* ipw = (const float*)d_in[7];
    const float* ipb = (const float*)d_in[8];
    const float* opw = (const float*)d_in[9];
    const float* opb = (const float*)d_in[10];
    const float* lw  = (const float*)d_in[11];
    const float* lb  = (const float*)d_in[12];
    float* out = (float*)d_out;

    // workspace carve-up (~214 MB)
    char* p = (char*)d_ws;
    unsigned short* xbs = (unsigned short*)p;                 // [4][N,64]  bf16  25.6 MB
    unsigned short* z1  = (unsigned short*)(p + 25600000);    // [4][N,64]  bf16  25.6 MB
    unsigned short* y1b = (unsigned short*)(p + 51200000);    // [4][N,128] bf16  51.2 MB
    unsigned short* z2  = (unsigned short*)(p + 102400000);   // [4][N,128] bf16  51.2 MB
    unsigned int*   pairs = (unsigned int*)(p + 102400000);   // [4][E] uint 12.8 MB (alias z2; dead before agg2)
    unsigned short* y2b = (unsigned short*)(p + 153600000);   // [4][N,128] bf16  51.2 MB
    char* meta = p + 204800000;
    int*   off  = (int*)meta;                                 // [4][N+1]
    float* dinv = (float*)(off + 4 * (Nn + 1));               // [4][N]
    int*   btot  = (int*)(dinv + 4 * Nn);                     // [4][NBK]
    int*   bbase = btot + 4 * NBK;                            // [4][NBK]
    int*   bcur  = bbase + 4 * NBK;                           // [4][NBK]
    unsigned short* srcs = (unsigned short*)(bcur + 4 * NBK); // [4][E] ushort 6.4 MB
    float* emb    = (float*)(srcs + (size_t)4 * En);          // [G,B,H]
    float* cnt    = emb + Gn * Bq * Hn;                       // [G,B]
    float* pooled = cnt + Gn * Bq;                            // [G,H]

    hipMemsetAsync(btot, 0, 4 * NBK * sizeof(int), stream);
    hipMemsetAsync(emb, 0, Gn * Bq * Hn * sizeof(float), stream);
    hipMemsetAsync(cnt, 0, Gn * Bq * sizeof(float), stream);
    hipMemsetAsync(pooled, 0, Gn * Hn * sizeof(float), stream);

    const int agGrid = (Nn + 7) / 8;                 // 6250
    const int mmGrid = (Nn + 31) / 32;               // 1563
    const int plGrid = (Nn + 63) / 64;               // 782
    const int ctGrid = (Nn * 16 + 255) / 256;        // 3125

    // CSR build: totals -> bases -> bucketize -> fused (count+scan+off/dinv+fill)
    k_btot<<<dim3(EB, Gn), 256, 0, stream>>>(ei, btot);
    k_bbase<<<Gn, 256, 0, stream>>>(btot, bbase, bcur);
    k_bucket<<<dim3(EB, Gn), 256, 0, stream>>>(ei, bcur, pairs);
    k_fillb2<<<dim3(NBK, Gn), 256, 0, stream>>>(pairs, bbase, btot, off, dinv, srcs);

    // GCN layers, all graphs per launch
    k_cast<<<dim3(ctGrid, Gn), 256, 0, stream>>>(x, dinv, xbs);
    k_agg1<<<dim3(agGrid, Gn), 256, 0, stream>>>(xbs, off, srcs, dinv, z1);
    k_mmfma<64, true><<<dim3(mmGrid, Gn), 256, 0, stream>>>(z1, W1, b1, dinv, y1b);
    k_agg2<<<dim3(agGrid, Gn), 256, 0, stream>>>(y1b, off, srcs, dinv, z2);
    k_mmfma<128, false><<<dim3(mmGrid, Gn), 256, 0, stream>>>(z2, W2, b2, dinv, y2b);
    k_pool<<<dim3(plGrid, Gn), 128, 0, stream>>>(y2b, bat, emb, cnt);

    k_attn<<<Bq, 128, 0, stream>>>(emb, cnt, ipw, ipb, opw, opb, pooled);
    k_final<<<(NNODES + 3) / 4, 256, 0, stream>>>(pooled, lw, lb, out);
}